// Round 9
// baseline (367.257 us; speedup 1.0000x reference)
//
#include <hip/hip_runtime.h>

#define WW 12
#define CH 32    // CIN == CMID == COUT == 32
#define KERN 3
#define SBT 256    // scan block size (two-level scan; needs ceil(N/SBT) <= SBT)
#define ROWB 384   // bytes per fp8 row = WW*CH; elements per bf16 row

typedef __attribute__((ext_vector_type(8))) short short8v;
typedef __attribute__((ext_vector_type(4))) short short4v;
typedef __attribute__((ext_vector_type(4))) float f32x4;

__device__ __forceinline__ unsigned short bf16rne(float v) {
  unsigned int u = __float_as_uint(v);
  return (unsigned short)((u + 0x7FFFu + ((u >> 16) & 1u)) >> 16);
}
__device__ __forceinline__ float bf16tof(unsigned int b) {
  return __uint_as_float(b << 16);
}

// exact-RNE f32 -> fp8 e4m3 (OCP, saturating, no NaN production)
__device__ __forceinline__ unsigned char fp8e4m3(float x) {
  unsigned int u = __float_as_uint(x);
  unsigned int s = (u >> 24) & 0x80u;
  float ax = fabsf(x);
  if (ax >= 464.f) return (unsigned char)(s | 0x7E);       // 448
  if (ax < 0.015625f) {                                    // subnormal: m = RNE(ax*512)
    int m = __float2int_rn(ax * 512.f);
    return (unsigned char)(s | (unsigned)m);               // m==8 carries to e=1,m=0
  }
  unsigned int au = u & 0x7fffffffu;
  au += 0x7FFFFu + ((au >> 20) & 1u);                      // RNE on 20 dropped bits
  int e = (int)(au >> 23) - 127 + 7;
  unsigned int m = (au >> 20) & 7u;
  if (e > 15 || (e == 15 && m == 7)) return (unsigned char)(s | 0x7E);
  return (unsigned char)(s | ((unsigned)e << 3) | m);
}

// decode 4 fp8 from one dword, fused multiply-accumulate into acc[0..3]
__device__ __forceinline__ void dec4fma(unsigned int u, float wh, float* acc) {
#if __has_builtin(__builtin_amdgcn_cvt_pk_f32_fp8)
  auto lo = __builtin_amdgcn_cvt_pk_f32_fp8((int)u, false);  // bytes 0,1
  auto hi = __builtin_amdgcn_cvt_pk_f32_fp8((int)u, true);   // bytes 2,3
  acc[0] = fmaf(wh, lo[0], acc[0]);
  acc[1] = fmaf(wh, lo[1], acc[1]);
  acc[2] = fmaf(wh, hi[0], acc[2]);
  acc[3] = fmaf(wh, hi[1], acc[3]);
#else
#pragma unroll
  for (int j = 0; j < 4; ++j) {
    unsigned int b = (u >> (8 * j)) & 0xffu;
    float f = __uint_as_float(((b & 0x80u) << 24) | ((b & 0x7fu) << 20)) * 0x1.0p120f;
    acc[j] = fmaf(wh, f, acc[j]);
  }
#endif
}

// ---------------------------------------------------------------------------
// K1: cnt[dst] += 1   (4B histogram atomic)
__global__ void cnt_kernel(const int* __restrict__ dst, int* __restrict__ cnt, int E) {
  int e = blockIdx.x * blockDim.x + threadIdx.x;
  if (e < E) atomicAdd(&cnt[dst[e]], 1);
}

// K2a: per-block reduction of counts -> bsum[b]
__global__ void scanA_kernel(const int* __restrict__ cnt, int* __restrict__ bsum, int N) {
  __shared__ int red[SBT];
  int i = blockIdx.x * SBT + threadIdx.x;
  red[threadIdx.x] = (i < N) ? cnt[i] : 0;
  __syncthreads();
  for (int o = SBT / 2; o > 0; o >>= 1) {
    if (threadIdx.x < o) red[threadIdx.x] += red[threadIdx.x + o];
    __syncthreads();
  }
  if (threadIdx.x == 0) bsum[blockIdx.x] = red[0];
}

// K2b: single-block exclusive scan of bsum (nb <= SBT); writes rowptr[N]=total
__global__ void scanB_kernel(int* __restrict__ bsum, int* __restrict__ rowptr,
                             int nb, int N) {
  __shared__ int tmp[SBT];
  int tid = threadIdx.x;
  int v = (tid < nb) ? bsum[tid] : 0;
  tmp[tid] = v;
  __syncthreads();
  for (int o = 1; o < SBT; o <<= 1) {
    int t = (tid >= o) ? tmp[tid - o] : 0;
    __syncthreads();
    tmp[tid] += t;
    __syncthreads();
  }
  if (tid < nb) bsum[tid] = tmp[tid] - v;        // exclusive block offsets
  if (tid == SBT - 1) rowptr[N] = tmp[SBT - 1];  // grand total
}

// K2c: per-block LDS ladder + block offset -> rowptr/wptr
__global__ void scanC_kernel(const int* __restrict__ cnt, const int* __restrict__ bsum,
                             int* __restrict__ rowptr, int* __restrict__ wptr, int N) {
  __shared__ int tmp[SBT];
  int tid = threadIdx.x;
  int i = blockIdx.x * SBT + tid;
  int v = (i < N) ? cnt[i] : 0;
  tmp[tid] = v;
  __syncthreads();
  for (int o = 1; o < SBT; o <<= 1) {
    int t = (tid >= o) ? tmp[tid - o] : 0;
    __syncthreads();
    tmp[tid] += t;
    __syncthreads();
  }
  if (i < N) {
    int ex = bsum[blockIdx.x] + tmp[tid] - v;
    rowptr[i] = ex;
    wptr[i] = ex;
  }
}

// K3: scatter edges into CSR slots as 4B records (src<<16 | bf16(Ew)).
//     Requires N <= 65536 (here N = 50000).
__global__ void fill_kernel(const int* __restrict__ src, const int* __restrict__ dst,
                            const float* __restrict__ Ew,
                            int* __restrict__ wptr, unsigned int* __restrict__ epair, int E) {
  int e = blockIdx.x * blockDim.x + threadIdx.x;
  if (e < E) {
    int d = dst[e];
    int pos = atomicAdd(&wptr[d], 1);
    epair[pos] = ((unsigned int)src[e] << 16) | bf16rne(Ew[e]);
  }
}

// K3b: per-node deg = sum of bf16(Ew) over own CSR bucket -> dinv[n]
__global__ void degsum_kernel(const int* __restrict__ rowptr,
                              const unsigned int* __restrict__ epair,
                              float* __restrict__ dinv, int N) {
  int n = blockIdx.x * blockDim.x + threadIdx.x;
  if (n >= N) return;
  float s = 0.f;
  int i1 = rowptr[n + 1];
  for (int i = rowptr[n]; i < i1; ++i) s += bf16tof(epair[i] & 0xffffu);
  dinv[n] = (s > 0.f) ? rsqrtf(fmaxf(s, 1e-12f)) : 0.f;
}

// K4: pack x (w,n,c) fp32 -> xt (n, w*32+c) bf16  AND  xq (n, w*32+c) fp8.
//     blockIdx.y == w.  blockIdx.y==0 low ids also pack MFMA weight fragments.
__global__ void pack_kernel(const float* __restrict__ x, const float* __restrict__ Wcheb,
                            const float* __restrict__ Wconv,
                            unsigned short* __restrict__ xt, unsigned char* __restrict__ xq,
                            unsigned short* __restrict__ wb01, unsigned short* __restrict__ wbc,
                            int N) {
  int id = blockIdx.x * blockDim.x + threadIdx.x;   // over N*CH
  int w = blockIdx.y;
  if (id < N * CH) {
    int n = id >> 5;
    int c = id & 31;
    float v = x[(size_t)w * N * CH + id];
    xt[(size_t)n * ROWB + w * CH + c] = bf16rne(v);
    xq[(size_t)n * ROWB + w * CH + c] = fp8e4m3(v);
  }
  if (w == 0) {
    if (id < 12 * 2 * 2 * 64 * 8) {
      int j = id & 7, l = (id >> 3) & 63, h = (id >> 9) & 1, m = (id >> 10) & 1, ww = id >> 11;
      int k = ((l >> 4) << 3) + j;
      int d = (l & 15) + (h << 4);
      wb01[id] = bf16rne(Wcheb[((size_t)(ww * 2 + m) * 32 + k) * 32 + d]);
    } else if (id < 24576 + 3 * 2 * 64 * 8) {
      int i2 = id - 24576;
      int j = i2 & 7, l = (i2 >> 3) & 63, h = (i2 >> 9) & 1, k = i2 >> 10;
      int c = ((l >> 4) << 3) + j;
      int o = (l & 15) + (h << 4);
      wbc[i2] = bf16rne(Wconv[((size_t)(o * 32 + c)) * 3 + k]);
    }
  }
}

// K5: gather  zt[n,p](bf16) = sum_{e: dst=n} (-dinv[src]*Ew*dinv[n]) * fp8(x)[src, p]
//     one node per wave; lane l&31 owns bytes [12l,12l+12) of the 384B row;
//     halves split the edge list, combined by shfl_xor(32).
__global__ __launch_bounds__(256) void gather_kernel(
    const int* __restrict__ rowptr, const unsigned int* __restrict__ epair,
    const float* __restrict__ dinv,
    const unsigned char* __restrict__ xq, unsigned short* __restrict__ zt, int N) {
  int gt = blockIdx.x * blockDim.x + threadIdx.x;
  int n = gt >> 6;
  if (n >= N) return;
  int lane = gt & 63;
  int half = lane >> 5;
  int l = lane & 31;

  const float ndinv = -dinv[n];   // fold dst factor and the minus sign

  float acc[WW];
#pragma unroll
  for (int j = 0; j < WW; ++j) acc[j] = 0.f;

  int i = rowptr[n] + half;
  const int i1 = rowptr[n + 1];
  for (; i + 2 < i1; i += 4) {        // 2 edges per half per iteration
    unsigned int e0 = epair[i];
    unsigned int e1 = epair[i + 2];
    int s0 = e0 >> 16, s1 = e1 >> 16;
    const unsigned int* p0 = (const unsigned int*)(xq + (size_t)s0 * ROWB + l * 12);
    const unsigned int* p1 = (const unsigned int*)(xq + (size_t)s1 * ROWB + l * 12);
    unsigned int a0 = p0[0], a1 = p0[1], a2 = p0[2];
    unsigned int b0 = p1[0], b1 = p1[1], b2 = p1[2];
    float w0 = ndinv * bf16tof(e0 & 0xffffu) * dinv[s0];
    float w1 = ndinv * bf16tof(e1 & 0xffffu) * dinv[s1];
    dec4fma(a0, w0, acc + 0);
    dec4fma(a1, w0, acc + 4);
    dec4fma(a2, w0, acc + 8);
    dec4fma(b0, w1, acc + 0);
    dec4fma(b1, w1, acc + 4);
    dec4fma(b2, w1, acc + 8);
  }
  if (i < i1) {
    unsigned int e0 = epair[i];
    int s0 = e0 >> 16;
    const unsigned int* p0 = (const unsigned int*)(xq + (size_t)s0 * ROWB + l * 12);
    unsigned int a0 = p0[0], a1 = p0[1], a2 = p0[2];
    float w0 = ndinv * bf16tof(e0 & 0xffffu) * dinv[s0];
    dec4fma(a0, w0, acc + 0);
    dec4fma(a1, w0, acc + 4);
    dec4fma(a2, w0, acc + 8);
  }
#pragma unroll
  for (int j = 0; j < WW; ++j) acc[j] += __shfl_xor(acc[j], 32);

  if (half == 0) {
    unsigned short* q = zt + (size_t)n * ROWB + l * 12;
    short4v o0, o1, o2;
#pragma unroll
    for (int j = 0; j < 4; ++j) {
      o0[j] = (short)bf16rne(acc[j]);
      o1[j] = (short)bf16rne(acc[4 + j]);
      o2[j] = (short)bf16rne(acc[8 + j]);
    }
    *(short4v*)(q) = o0;
    *(short4v*)(q + 4) = o1;
    *(short4v*)(q + 8) = o2;
  }
}

// K6 (fused mix+conv, MFMA, rolling LDS ring): per wave, 16 nodes.
//  computeH(w): H[w] = bcheb[w] + X[w]@W0[w] + Z[w]@W1[w]  -> LDS ring slot w&3
//  convT(t):    OUT[t] = leaky( sum_k H[t+k-1] @ Wc[k] + bconv )
__global__ __launch_bounds__(256) void mc_kernel(
    const unsigned short* __restrict__ xt, const unsigned short* __restrict__ zt,
    const unsigned short* __restrict__ wb01, const unsigned short* __restrict__ wbc,
    const float* __restrict__ bcheb, const float* __restrict__ bconv,
    float* __restrict__ out, int N) {
  __shared__ __align__(16) unsigned short hts[4][4][16][40];  // [wave][ring][row][40-pad]
  const int wid = threadIdx.x >> 6;
  const int lane = threadIdx.x & 63;
  const int n0 = (blockIdx.x * 4 + wid) * 16;
  if (n0 >= N) return;
  const int kg = lane >> 4;
  const int arow = lane & 15;
  const int rrow = min(n0 + arow, N - 1);   // clamp tail reads

  short8v wcf0[3], wcf1[3];
#pragma unroll
  for (int k = 0; k < 3; ++k) {
    wcf0[k] = *(const short8v*)(wbc + (((k * 2 + 0) * 64 + lane) << 3));
    wcf1[k] = *(const short8v*)(wbc + (((k * 2 + 1) * 64 + lane) << 3));
  }
  const float bc0 = bconv[arow];
  const float bc1 = bconv[arow + 16];

  auto computeH = [&](int w) {
    const size_t fofs = (size_t)rrow * ROWB + w * CH + kg * 8;
    short8v xf = *(const short8v*)(xt + fofs);
    short8v zf = *(const short8v*)(zt + fofs);
    unsigned short* hrow = &hts[wid][w & 3][0][0];
#pragma unroll
    for (int h = 0; h < 2; ++h) {
      short8v w0f = *(const short8v*)(wb01 + ((((w * 2 + 0) * 2 + h) * 64 + lane) << 3));
      short8v w1f = *(const short8v*)(wb01 + ((((w * 2 + 1) * 2 + h) * 64 + lane) << 3));
      f32x4 acc = {0.f, 0.f, 0.f, 0.f};
      acc = __builtin_amdgcn_mfma_f32_16x16x32_bf16(xf, w0f, acc, 0, 0, 0);
      acc = __builtin_amdgcn_mfma_f32_16x16x32_bf16(zf, w1f, acc, 0, 0, 0);
      const int d = arow + (h << 4);
      const float bias = bcheb[w * CH + d];
#pragma unroll
      for (int r = 0; r < 4; ++r) {
        hrow[(kg * 4 + r) * 40 + d] = bf16rne(acc[r] + bias);
      }
    }
  };

  auto convT = [&](int t) {
    f32x4 a0 = {0.f, 0.f, 0.f, 0.f};
    f32x4 a1 = {0.f, 0.f, 0.f, 0.f};
#pragma unroll
    for (int k = 0; k < 3; ++k) {
      int w = t + k - 1;
      if (w < 0 || w >= WW) continue;
      short8v hf = *(const short8v*)(&hts[wid][w & 3][arow][kg * 8]);
      a0 = __builtin_amdgcn_mfma_f32_16x16x32_bf16(hf, wcf0[k], a0, 0, 0, 0);
      a1 = __builtin_amdgcn_mfma_f32_16x16x32_bf16(hf, wcf1[k], a1, 0, 0, 0);
    }
#pragma unroll
    for (int r = 0; r < 4; ++r) {
      int node = n0 + kg * 4 + r;
      if (node >= N) continue;               // guard tail writes
      float v0 = a0[r] + bc0;
      float v1 = a1[r] + bc1;
      v0 = (v0 >= 0.f) ? v0 : 0.01f * v0;
      v1 = (v1 >= 0.f) ? v1 : 0.01f * v1;
      size_t o = ((size_t)node * WW + t) * CH;
      out[o + arow] = v0;
      out[o + arow + 16] = v1;
    }
  };

  computeH(0);
  computeH(1);
  convT(0);
  for (int w = 2; w < WW; ++w) {
    computeH(w);
    convT(w - 1);
  }
  convT(WW - 1);
}

// ---------------------------------------------------------------------------
extern "C" void kernel_launch(void* const* d_in, const int* in_sizes, int n_in,
                              void* d_out, int out_size, void* d_ws, size_t ws_size,
                              hipStream_t stream) {
  const float* x     = (const float*)d_in[0];
  const int*   A     = (const int*)d_in[1];
  const float* Ew    = (const float*)d_in[2];
  const float* Wcheb = (const float*)d_in[3];
  const float* bcheb = (const float*)d_in[4];
  const float* Wconv = (const float*)d_in[5];
  const float* bconv = (const float*)d_in[6];
  float* out = (float*)d_out;

  const int E = in_sizes[2];
  const int N = in_sizes[0] / (WW * CH);
  const int* srcA = A;
  const int* dstA = A + E;

  char* ws = (char*)d_ws;
  size_t off = 0;
  auto alloc = [&](size_t bytes) -> void* {
    void* p = ws + off;
    off += (bytes + 255) / 256 * 256;
    return p;
  };
  int*   cnt    = (int*)alloc((size_t)N * 4);
  int*   rowptr = (int*)alloc((size_t)(N + 1) * 4);
  int*   wptr   = (int*)alloc((size_t)N * 4);
  int*   bsum   = (int*)alloc((size_t)SBT * 4);
  float* dinv   = (float*)alloc((size_t)N * 4);
  unsigned int* epair = (unsigned int*)alloc((size_t)E * 4);
  unsigned short* xt   = (unsigned short*)alloc((size_t)N * ROWB * 2);
  unsigned char*  xq   = (unsigned char*)alloc((size_t)N * ROWB);
  unsigned short* zt   = (unsigned short*)alloc((size_t)N * ROWB * 2);
  unsigned short* wb01 = (unsigned short*)alloc((size_t)24576 * 2);
  unsigned short* wbc  = (unsigned short*)alloc((size_t)3072 * 2);
  (void)ws_size;

  hipMemsetAsync(cnt, 0, (size_t)N * 4, stream);

  cnt_kernel<<<(E + 255) / 256, 256, 0, stream>>>(dstA, cnt, E);

  const int nb = (N + SBT - 1) / SBT;   // 196 <= 256 for N=50000
  scanA_kernel<<<nb, SBT, 0, stream>>>(cnt, bsum, N);
  scanB_kernel<<<1, SBT, 0, stream>>>(bsum, rowptr, nb, N);
  scanC_kernel<<<nb, SBT, 0, stream>>>(cnt, bsum, rowptr, wptr, N);

  fill_kernel<<<(E + 255) / 256, 256, 0, stream>>>(srcA, dstA, Ew, wptr, epair, E);
  degsum_kernel<<<(N + 255) / 256, 256, 0, stream>>>(rowptr, epair, dinv, N);

  dim3 gpack((N * CH + 255) / 256, WW);
  pack_kernel<<<gpack, 256, 0, stream>>>(x, Wcheb, Wconv, xt, xq, wb01, wbc, N);

  long long gtot = (long long)N * 64;
  gather_kernel<<<(unsigned)((gtot + 255) / 256), 256, 0, stream>>>(rowptr, epair, dinv, xq, zt, N);

  int ntiles = (N + 15) / 16;            // 16-node wave tiles
  int mcblocks = (ntiles + 3) / 4;       // 4 waves per block
  mc_kernel<<<mcblocks, 256, 0, stream>>>(xt, zt, wb01, wbc, bcheb, bconv, out, N);
}

// Round 10
// 304.876 us; speedup vs baseline: 1.2046x; 1.2046x over previous
//
#include <hip/hip_runtime.h>

#define WW 12
#define CH 32    // CIN == CMID == COUT == 32
#define KERN 3
#define SBT 256    // scan block size (two-level scan; needs ceil(N/SBT) <= SBT)
#define ROWB 384   // bytes per fp8 row = WW*CH; elements per bf16 row

typedef __attribute__((ext_vector_type(8))) short short8v;
typedef __attribute__((ext_vector_type(4))) short short4v;
typedef __attribute__((ext_vector_type(4))) float f32x4;

__device__ __forceinline__ unsigned short bf16rne(float v) {
  unsigned int u = __float_as_uint(v);
  return (unsigned short)((u + 0x7FFFu + ((u >> 16) & 1u)) >> 16);
}
__device__ __forceinline__ float bf16tof(unsigned int b) {
  return __uint_as_float(b << 16);
}

// exact-RNE f32 -> fp8 e4m3 (OCP, saturating, no NaN production)
__device__ __forceinline__ unsigned char fp8e4m3(float x) {
  unsigned int u = __float_as_uint(x);
  unsigned int s = (u >> 24) & 0x80u;
  float ax = fabsf(x);
  if (ax >= 464.f) return (unsigned char)(s | 0x7E);       // 448
  if (ax < 0.015625f) {                                    // subnormal: m = RNE(ax*512)
    int m = __float2int_rn(ax * 512.f);
    return (unsigned char)(s | (unsigned)m);               // m==8 carries to e=1,m=0
  }
  unsigned int au = u & 0x7fffffffu;
  au += 0x7FFFFu + ((au >> 20) & 1u);                      // RNE on 20 dropped bits
  int e = (int)(au >> 23) - 127 + 7;
  unsigned int m = (au >> 20) & 7u;
  if (e > 15 || (e == 15 && m == 7)) return (unsigned char)(s | 0x7E);
  return (unsigned char)(s | ((unsigned)e << 3) | m);
}

// decode 4 fp8 from one dword, fused multiply-accumulate into acc[0..3]
__device__ __forceinline__ void dec4fma(unsigned int u, float wh, float* acc) {
#if __has_builtin(__builtin_amdgcn_cvt_pk_f32_fp8)
  auto lo = __builtin_amdgcn_cvt_pk_f32_fp8((int)u, false);  // bytes 0,1
  auto hi = __builtin_amdgcn_cvt_pk_f32_fp8((int)u, true);   // bytes 2,3
  acc[0] = fmaf(wh, lo[0], acc[0]);
  acc[1] = fmaf(wh, lo[1], acc[1]);
  acc[2] = fmaf(wh, hi[0], acc[2]);
  acc[3] = fmaf(wh, hi[1], acc[3]);
#else
#pragma unroll
  for (int j = 0; j < 4; ++j) {
    unsigned int b = (u >> (8 * j)) & 0xffu;
    float f = __uint_as_float(((b & 0x80u) << 24) | ((b & 0x7fu) << 20)) * 0x1.0p120f;
    acc[j] = fmaf(wh, f, acc[j]);
  }
#endif
}

// ---------------------------------------------------------------------------
// K1: degcnt[dst] += (1<<32)|fix25(Ew); coalesced rank[e] = old count (hi32).
//     The ONLY atomic pass. count hi32, fixed-point weighted degree lo32.
__global__ void rank_kernel(const int* __restrict__ dst, const float* __restrict__ Ew,
                            unsigned long long* __restrict__ degcnt,
                            unsigned short* __restrict__ rank, int E) {
  int e = blockIdx.x * blockDim.x + threadIdx.x;
  if (e < E) {
    unsigned int q = (unsigned int)__float2int_rn(Ew[e] * 33554432.f);
    unsigned long long old = atomicAdd(&degcnt[dst[e]], (1ULL << 32) | (unsigned long long)q);
    rank[e] = (unsigned short)(old >> 32);
  }
}

// K2a: per-block reduction of counts -> bsum[b]
__global__ void scanA_kernel(const unsigned long long* __restrict__ degcnt,
                             int* __restrict__ bsum, int N) {
  __shared__ int red[SBT];
  int i = blockIdx.x * SBT + threadIdx.x;
  red[threadIdx.x] = (i < N) ? (int)(degcnt[i] >> 32) : 0;
  __syncthreads();
  for (int o = SBT / 2; o > 0; o >>= 1) {
    if (threadIdx.x < o) red[threadIdx.x] += red[threadIdx.x + o];
    __syncthreads();
  }
  if (threadIdx.x == 0) bsum[blockIdx.x] = red[0];
}

// K2b: single-block exclusive scan of bsum (nb <= SBT); writes rowptr[N]=total
__global__ void scanB_kernel(int* __restrict__ bsum, int* __restrict__ rowptr,
                             int nb, int N) {
  __shared__ int tmp[SBT];
  int tid = threadIdx.x;
  int v = (tid < nb) ? bsum[tid] : 0;
  tmp[tid] = v;
  __syncthreads();
  for (int o = 1; o < SBT; o <<= 1) {
    int t = (tid >= o) ? tmp[tid - o] : 0;
    __syncthreads();
    tmp[tid] += t;
    __syncthreads();
  }
  if (tid < nb) bsum[tid] = tmp[tid] - v;        // exclusive block offsets
  if (tid == SBT - 1) rowptr[N] = tmp[SBT - 1];  // grand total
}

// K2c: per-block LDS ladder + block offset -> rowptr
__global__ void scanC_kernel(const unsigned long long* __restrict__ degcnt,
                             const int* __restrict__ bsum,
                             int* __restrict__ rowptr, int N) {
  __shared__ int tmp[SBT];
  int tid = threadIdx.x;
  int i = blockIdx.x * SBT + tid;
  int v = (i < N) ? (int)(degcnt[i] >> 32) : 0;
  tmp[tid] = v;
  __syncthreads();
  for (int o = 1; o < SBT; o <<= 1) {
    int t = (tid >= o) ? tmp[tid - o] : 0;
    __syncthreads();
    tmp[tid] += t;
    __syncthreads();
  }
  if (i < N) rowptr[i] = bsum[blockIdx.x] + tmp[tid] - v;
}

// K3: ATOMIC-FREE scatter: pos = rowptr[dst] + rank[e]; record = src<<16 | bf16(w_hat).
//     w_hat computed here from degcnt lo32 (L2-resident). Requires N <= 65536.
__global__ void fill_kernel(const int* __restrict__ src, const int* __restrict__ dst,
                            const float* __restrict__ Ew,
                            const unsigned long long* __restrict__ degcnt,
                            const int* __restrict__ rowptr,
                            const unsigned short* __restrict__ rank,
                            unsigned int* __restrict__ epair, int E) {
  int e = blockIdx.x * blockDim.x + threadIdx.x;
  if (e < E) {
    int s = src[e], d = dst[e];
    float ds = (float)(unsigned int)degcnt[s] * (1.f / 33554432.f);
    float dd = (float)(unsigned int)degcnt[d] * (1.f / 33554432.f);
    float is = (ds > 0.f) ? rsqrtf(fmaxf(ds, 1e-12f)) : 0.f;
    float id_ = (dd > 0.f) ? rsqrtf(fmaxf(dd, 1e-12f)) : 0.f;
    float wh = -is * Ew[e] * id_;
    int pos = rowptr[d] + rank[e];
    epair[pos] = ((unsigned int)s << 16) | bf16rne(wh);
  }
}

// K4: pack x (w,n,c) fp32 -> xt (n, w*32+c) bf16  AND  xq (n, w*32+c) fp8.
//     blockIdx.y == w.  blockIdx.y==0 low ids also pack MFMA weight fragments.
__global__ void pack_kernel(const float* __restrict__ x, const float* __restrict__ Wcheb,
                            const float* __restrict__ Wconv,
                            unsigned short* __restrict__ xt, unsigned char* __restrict__ xq,
                            unsigned short* __restrict__ wb01, unsigned short* __restrict__ wbc,
                            int N) {
  int id = blockIdx.x * blockDim.x + threadIdx.x;   // over N*CH
  int w = blockIdx.y;
  if (id < N * CH) {
    int n = id >> 5;
    int c = id & 31;
    float v = x[(size_t)w * N * CH + id];
    xt[(size_t)n * ROWB + w * CH + c] = bf16rne(v);
    xq[(size_t)n * ROWB + w * CH + c] = fp8e4m3(v);
  }
  if (w == 0) {
    if (id < 12 * 2 * 2 * 64 * 8) {
      int j = id & 7, l = (id >> 3) & 63, h = (id >> 9) & 1, m = (id >> 10) & 1, ww = id >> 11;
      int k = ((l >> 4) << 3) + j;
      int d = (l & 15) + (h << 4);
      wb01[id] = bf16rne(Wcheb[((size_t)(ww * 2 + m) * 32 + k) * 32 + d]);
    } else if (id < 24576 + 3 * 2 * 64 * 8) {
      int i2 = id - 24576;
      int j = i2 & 7, l = (i2 >> 3) & 63, h = (i2 >> 9) & 1, k = i2 >> 10;
      int c = ((l >> 4) << 3) + j;
      int o = (l & 15) + (h << 4);
      wbc[i2] = bf16rne(Wconv[((size_t)(o * 32 + c)) * 3 + k]);
    }
  }
}

// K5: gather  zt[n,p](bf16) = sum_{e: dst=n} w_hat(e) * fp8(x)[src, p]
//     one node per wave; lane l&31 owns bytes [12l,12l+12) of the 384B row;
//     halves split the edge list, combined by shfl_xor(32).
__global__ __launch_bounds__(256) void gather_kernel(
    const int* __restrict__ rowptr, const unsigned int* __restrict__ epair,
    const unsigned char* __restrict__ xq, unsigned short* __restrict__ zt, int N) {
  int gt = blockIdx.x * blockDim.x + threadIdx.x;
  int n = gt >> 6;
  if (n >= N) return;
  int lane = gt & 63;
  int half = lane >> 5;
  int l = lane & 31;

  float acc[WW];
#pragma unroll
  for (int j = 0; j < WW; ++j) acc[j] = 0.f;

  int i = rowptr[n] + half;
  const int i1 = rowptr[n + 1];
  for (; i + 2 < i1; i += 4) {        // 2 edges per half per iteration
    unsigned int e0 = epair[i];
    unsigned int e1 = epair[i + 2];
    int s0 = e0 >> 16, s1 = e1 >> 16;
    const unsigned int* p0 = (const unsigned int*)(xq + (size_t)s0 * ROWB + l * 12);
    const unsigned int* p1 = (const unsigned int*)(xq + (size_t)s1 * ROWB + l * 12);
    unsigned int a0 = p0[0], a1 = p0[1], a2 = p0[2];
    unsigned int b0 = p1[0], b1 = p1[1], b2 = p1[2];
    float w0 = bf16tof(e0 & 0xffffu);
    float w1 = bf16tof(e1 & 0xffffu);
    dec4fma(a0, w0, acc + 0);
    dec4fma(a1, w0, acc + 4);
    dec4fma(a2, w0, acc + 8);
    dec4fma(b0, w1, acc + 0);
    dec4fma(b1, w1, acc + 4);
    dec4fma(b2, w1, acc + 8);
  }
  if (i < i1) {
    unsigned int e0 = epair[i];
    int s0 = e0 >> 16;
    const unsigned int* p0 = (const unsigned int*)(xq + (size_t)s0 * ROWB + l * 12);
    unsigned int a0 = p0[0], a1 = p0[1], a2 = p0[2];
    float w0 = bf16tof(e0 & 0xffffu);
    dec4fma(a0, w0, acc + 0);
    dec4fma(a1, w0, acc + 4);
    dec4fma(a2, w0, acc + 8);
  }
#pragma unroll
  for (int j = 0; j < WW; ++j) acc[j] += __shfl_xor(acc[j], 32);

  if (half == 0) {
    unsigned short* q = zt + (size_t)n * ROWB + l * 12;
    short4v o0, o1, o2;
#pragma unroll
    for (int j = 0; j < 4; ++j) {
      o0[j] = (short)bf16rne(acc[j]);
      o1[j] = (short)bf16rne(acc[4 + j]);
      o2[j] = (short)bf16rne(acc[8 + j]);
    }
    *(short4v*)(q) = o0;
    *(short4v*)(q + 4) = o1;
    *(short4v*)(q + 8) = o2;
  }
}

// K6 (fused mix+conv, MFMA, rolling LDS ring): per wave, 16 nodes.
//  computeH(w): H[w] = bcheb[w] + X[w]@W0[w] + Z[w]@W1[w]  -> LDS ring slot w&3
//  convT(t):    OUT[t] = leaky( sum_k H[t+k-1] @ Wc[k] + bconv )
__global__ __launch_bounds__(256) void mc_kernel(
    const unsigned short* __restrict__ xt, const unsigned short* __restrict__ zt,
    const unsigned short* __restrict__ wb01, const unsigned short* __restrict__ wbc,
    const float* __restrict__ bcheb, const float* __restrict__ bconv,
    float* __restrict__ out, int N) {
  __shared__ __align__(16) unsigned short hts[4][4][16][40];  // [wave][ring][row][40-pad]
  const int wid = threadIdx.x >> 6;
  const int lane = threadIdx.x & 63;
  const int n0 = (blockIdx.x * 4 + wid) * 16;
  if (n0 >= N) return;
  const int kg = lane >> 4;
  const int arow = lane & 15;
  const int rrow = min(n0 + arow, N - 1);   // clamp tail reads

  short8v wcf0[3], wcf1[3];
#pragma unroll
  for (int k = 0; k < 3; ++k) {
    wcf0[k] = *(const short8v*)(wbc + (((k * 2 + 0) * 64 + lane) << 3));
    wcf1[k] = *(const short8v*)(wbc + (((k * 2 + 1) * 64 + lane) << 3));
  }
  const float bc0 = bconv[arow];
  const float bc1 = bconv[arow + 16];

  auto computeH = [&](int w) {
    const size_t fofs = (size_t)rrow * ROWB + w * CH + kg * 8;
    short8v xf = *(const short8v*)(xt + fofs);
    short8v zf = *(const short8v*)(zt + fofs);
    unsigned short* hrow = &hts[wid][w & 3][0][0];
#pragma unroll
    for (int h = 0; h < 2; ++h) {
      short8v w0f = *(const short8v*)(wb01 + ((((w * 2 + 0) * 2 + h) * 64 + lane) << 3));
      short8v w1f = *(const short8v*)(wb01 + ((((w * 2 + 1) * 2 + h) * 64 + lane) << 3));
      f32x4 acc = {0.f, 0.f, 0.f, 0.f};
      acc = __builtin_amdgcn_mfma_f32_16x16x32_bf16(xf, w0f, acc, 0, 0, 0);
      acc = __builtin_amdgcn_mfma_f32_16x16x32_bf16(zf, w1f, acc, 0, 0, 0);
      const int d = arow + (h << 4);
      const float bias = bcheb[w * CH + d];
#pragma unroll
      for (int r = 0; r < 4; ++r) {
        hrow[(kg * 4 + r) * 40 + d] = bf16rne(acc[r] + bias);
      }
    }
  };

  auto convT = [&](int t) {
    f32x4 a0 = {0.f, 0.f, 0.f, 0.f};
    f32x4 a1 = {0.f, 0.f, 0.f, 0.f};
#pragma unroll
    for (int k = 0; k < 3; ++k) {
      int w = t + k - 1;
      if (w < 0 || w >= WW) continue;
      short8v hf = *(const short8v*)(&hts[wid][w & 3][arow][kg * 8]);
      a0 = __builtin_amdgcn_mfma_f32_16x16x32_bf16(hf, wcf0[k], a0, 0, 0, 0);
      a1 = __builtin_amdgcn_mfma_f32_16x16x32_bf16(hf, wcf1[k], a1, 0, 0, 0);
    }
#pragma unroll
    for (int r = 0; r < 4; ++r) {
      int node = n0 + kg * 4 + r;
      if (node >= N) continue;               // guard tail writes
      float v0 = a0[r] + bc0;
      float v1 = a1[r] + bc1;
      v0 = (v0 >= 0.f) ? v0 : 0.01f * v0;
      v1 = (v1 >= 0.f) ? v1 : 0.01f * v1;
      size_t o = ((size_t)node * WW + t) * CH;
      out[o + arow] = v0;
      out[o + arow + 16] = v1;
    }
  };

  computeH(0);
  computeH(1);
  convT(0);
  for (int w = 2; w < WW; ++w) {
    computeH(w);
    convT(w - 1);
  }
  convT(WW - 1);
}

// ---------------------------------------------------------------------------
extern "C" void kernel_launch(void* const* d_in, const int* in_sizes, int n_in,
                              void* d_out, int out_size, void* d_ws, size_t ws_size,
                              hipStream_t stream) {
  const float* x     = (const float*)d_in[0];
  const int*   A     = (const int*)d_in[1];
  const float* Ew    = (const float*)d_in[2];
  const float* Wcheb = (const float*)d_in[3];
  const float* bcheb = (const float*)d_in[4];
  const float* Wconv = (const float*)d_in[5];
  const float* bconv = (const float*)d_in[6];
  float* out = (float*)d_out;

  const int E = in_sizes[2];
  const int N = in_sizes[0] / (WW * CH);
  const int* srcA = A;
  const int* dstA = A + E;

  char* ws = (char*)d_ws;
  size_t off = 0;
  auto alloc = [&](size_t bytes) -> void* {
    void* p = ws + off;
    off += (bytes + 255) / 256 * 256;
    return p;
  };
  unsigned long long* degcnt = (unsigned long long*)alloc((size_t)N * 8);
  int*   rowptr = (int*)alloc((size_t)(N + 1) * 4);
  int*   bsum   = (int*)alloc((size_t)SBT * 4);
  unsigned short* rank = (unsigned short*)alloc((size_t)E * 2);
  unsigned int* epair = (unsigned int*)alloc((size_t)E * 4);
  unsigned short* xt   = (unsigned short*)alloc((size_t)N * ROWB * 2);
  unsigned char*  xq   = (unsigned char*)alloc((size_t)N * ROWB);
  unsigned short* zt   = (unsigned short*)alloc((size_t)N * ROWB * 2);
  unsigned short* wb01 = (unsigned short*)alloc((size_t)24576 * 2);
  unsigned short* wbc  = (unsigned short*)alloc((size_t)3072 * 2);
  (void)ws_size;

  hipMemsetAsync(degcnt, 0, (size_t)N * 8, stream);

  rank_kernel<<<(E + 255) / 256, 256, 0, stream>>>(dstA, Ew, degcnt, rank, E);

  const int nb = (N + SBT - 1) / SBT;   // 196 <= 256 for N=50000
  scanA_kernel<<<nb, SBT, 0, stream>>>(degcnt, bsum, N);
  scanB_kernel<<<1, SBT, 0, stream>>>(bsum, rowptr, nb, N);
  scanC_kernel<<<nb, SBT, 0, stream>>>(degcnt, bsum, rowptr, N);

  fill_kernel<<<(E + 255) / 256, 256, 0, stream>>>(srcA, dstA, Ew, degcnt, rowptr, rank, epair, E);

  dim3 gpack((N * CH + 255) / 256, WW);
  pack_kernel<<<gpack, 256, 0, stream>>>(x, Wcheb, Wconv, xt, xq, wb01, wbc, N);

  long long gtot = (long long)N * 64;
  gather_kernel<<<(unsigned)((gtot + 255) / 256), 256, 0, stream>>>(rowptr, epair, xq, zt, N);

  int ntiles = (N + 15) / 16;            // 16-node wave tiles
  int mcblocks = (ntiles + 3) / 4;       // 4 waves per block
  mc_kernel<<<mcblocks, 256, 0, stream>>>(xt, zt, wb01, wbc, bcheb, bconv, out, N);
}

// Round 11
// 301.500 us; speedup vs baseline: 1.2181x; 1.0112x over previous
//
#include <hip/hip_runtime.h>

#define WW 12
#define CH 32    // CIN == CMID == COUT == 32
#define KERN 3
#define SBT 256    // scan block size (two-level scan; needs ceil(N/SBT) <= SBT)
#define ROWB 384   // bytes per fp8 row = WW*CH; elements per bf16 row

typedef __attribute__((ext_vector_type(8))) short short8v;
typedef __attribute__((ext_vector_type(4))) short short4v;
typedef __attribute__((ext_vector_type(4))) float f32x4;

__device__ __forceinline__ unsigned short bf16rne(float v) {
  unsigned int u = __float_as_uint(v);
  return (unsigned short)((u + 0x7FFFu + ((u >> 16) & 1u)) >> 16);
}
__device__ __forceinline__ float bf16tof(unsigned int b) {
  return __uint_as_float(b << 16);
}

// exact-RNE f32 -> fp8 e4m3 (OCP, saturating, no NaN production)
__device__ __forceinline__ unsigned char fp8e4m3(float x) {
  unsigned int u = __float_as_uint(x);
  unsigned int s = (u >> 24) & 0x80u;
  float ax = fabsf(x);
  if (ax >= 464.f) return (unsigned char)(s | 0x7E);       // 448
  if (ax < 0.015625f) {                                    // subnormal: m = RNE(ax*512)
    int m = __float2int_rn(ax * 512.f);
    return (unsigned char)(s | (unsigned)m);               // m==8 carries to e=1,m=0
  }
  unsigned int au = u & 0x7fffffffu;
  au += 0x7FFFFu + ((au >> 20) & 1u);                      // RNE on 20 dropped bits
  int e = (int)(au >> 23) - 127 + 7;
  unsigned int m = (au >> 20) & 7u;
  if (e > 15 || (e == 15 && m == 7)) return (unsigned char)(s | 0x7E);
  return (unsigned char)(s | ((unsigned)e << 3) | m);
}

// decode 4 fp8 from one dword, fused multiply-accumulate into acc[0..3]
__device__ __forceinline__ void dec4fma(unsigned int u, float wh, float* acc) {
#if __has_builtin(__builtin_amdgcn_cvt_pk_f32_fp8)
  auto lo = __builtin_amdgcn_cvt_pk_f32_fp8((int)u, false);  // bytes 0,1
  auto hi = __builtin_amdgcn_cvt_pk_f32_fp8((int)u, true);   // bytes 2,3
  acc[0] = fmaf(wh, lo[0], acc[0]);
  acc[1] = fmaf(wh, lo[1], acc[1]);
  acc[2] = fmaf(wh, hi[0], acc[2]);
  acc[3] = fmaf(wh, hi[1], acc[3]);
#else
#pragma unroll
  for (int j = 0; j < 4; ++j) {
    unsigned int b = (u >> (8 * j)) & 0xffu;
    float f = __uint_as_float(((b & 0x80u) << 24) | ((b & 0x7fu) << 20)) * 0x1.0p120f;
    acc[j] = fmaf(wh, f, acc[j]);
  }
#endif
}

// ---------------------------------------------------------------------------
// K1 (FUSED rank + pack, grid-partitioned):
//  blocks [0, nbR):       degcnt[dst] += (1<<32)|fix25(Ew); rank[e] = old>>32
//  blocks [nbR, nbR+12*nbx): pack x -> xt(bf16) + xq(fp8); w==0 also packs weights
__global__ void rankpack_kernel(const int* __restrict__ dst, const float* __restrict__ Ew,
                                unsigned long long* __restrict__ degcnt,
                                unsigned short* __restrict__ rank,
                                const float* __restrict__ x, const float* __restrict__ Wcheb,
                                const float* __restrict__ Wconv,
                                unsigned short* __restrict__ xt, unsigned char* __restrict__ xq,
                                unsigned short* __restrict__ wb01, unsigned short* __restrict__ wbc,
                                int E, int N, int nbR, int nbx) {
  int blk = blockIdx.x;
  if (blk < nbR) {
    int e = blk * blockDim.x + threadIdx.x;
    if (e < E) {
      unsigned int q = (unsigned int)__float2int_rn(Ew[e] * 33554432.f);
      unsigned long long old = atomicAdd(&degcnt[dst[e]], (1ULL << 32) | (unsigned long long)q);
      rank[e] = (unsigned short)(old >> 32);
    }
    return;
  }
  int pid = blk - nbR;
  int w = pid / nbx;
  int id = (pid - w * nbx) * blockDim.x + threadIdx.x;
  if (id < N * CH) {
    int n = id >> 5;
    int c = id & 31;
    float v = x[(size_t)w * N * CH + id];
    xt[(size_t)n * ROWB + w * CH + c] = bf16rne(v);
    xq[(size_t)n * ROWB + w * CH + c] = fp8e4m3(v);
  }
  if (w == 0) {
    if (id < 12 * 2 * 2 * 64 * 8) {
      int j = id & 7, l = (id >> 3) & 63, h = (id >> 9) & 1, m = (id >> 10) & 1, ww = id >> 11;
      int k = ((l >> 4) << 3) + j;
      int d = (l & 15) + (h << 4);
      wb01[id] = bf16rne(Wcheb[((size_t)(ww * 2 + m) * 32 + k) * 32 + d]);
    } else if (id < 24576 + 3 * 2 * 64 * 8) {
      int i2 = id - 24576;
      int j = i2 & 7, l = (i2 >> 3) & 63, h = (i2 >> 9) & 1, k = i2 >> 10;
      int c = ((l >> 4) << 3) + j;
      int o = (l & 15) + (h << 4);
      wbc[i2] = bf16rne(Wconv[((size_t)(o * 32 + c)) * 3 + k]);
    }
  }
}

// K2a: per-block reduction of counts -> bsum[b]
__global__ void scanA_kernel(const unsigned long long* __restrict__ degcnt,
                             int* __restrict__ bsum, int N) {
  __shared__ int red[SBT];
  int i = blockIdx.x * SBT + threadIdx.x;
  red[threadIdx.x] = (i < N) ? (int)(degcnt[i] >> 32) : 0;
  __syncthreads();
  for (int o = SBT / 2; o > 0; o >>= 1) {
    if (threadIdx.x < o) red[threadIdx.x] += red[threadIdx.x + o];
    __syncthreads();
  }
  if (threadIdx.x == 0) bsum[blockIdx.x] = red[0];
}

// K2b: single-block exclusive scan of bsum (nb <= SBT); writes rowptr[N]=total
__global__ void scanB_kernel(int* __restrict__ bsum, int* __restrict__ rowptr,
                             int nb, int N) {
  __shared__ int tmp[SBT];
  int tid = threadIdx.x;
  int v = (tid < nb) ? bsum[tid] : 0;
  tmp[tid] = v;
  __syncthreads();
  for (int o = 1; o < SBT; o <<= 1) {
    int t = (tid >= o) ? tmp[tid - o] : 0;
    __syncthreads();
    tmp[tid] += t;
    __syncthreads();
  }
  if (tid < nb) bsum[tid] = tmp[tid] - v;        // exclusive block offsets
  if (tid == SBT - 1) rowptr[N] = tmp[SBT - 1];  // grand total
}

// K2c: per-block LDS ladder + block offset -> rowptr
__global__ void scanC_kernel(const unsigned long long* __restrict__ degcnt,
                             const int* __restrict__ bsum,
                             int* __restrict__ rowptr, int N) {
  __shared__ int tmp[SBT];
  int tid = threadIdx.x;
  int i = blockIdx.x * SBT + tid;
  int v = (i < N) ? (int)(degcnt[i] >> 32) : 0;
  tmp[tid] = v;
  __syncthreads();
  for (int o = 1; o < SBT; o <<= 1) {
    int t = (tid >= o) ? tmp[tid - o] : 0;
    __syncthreads();
    tmp[tid] += t;
    __syncthreads();
  }
  if (i < N) rowptr[i] = bsum[blockIdx.x] + tmp[tid] - v;
}

// K3: ATOMIC-FREE scatter: pos = rowptr[dst] + rank[e]; record = src<<16 | bf16(w_hat).
//     w_hat computed here from degcnt lo32 (L2-resident). Requires N <= 65536.
__global__ void fill_kernel(const int* __restrict__ src, const int* __restrict__ dst,
                            const float* __restrict__ Ew,
                            const unsigned long long* __restrict__ degcnt,
                            const int* __restrict__ rowptr,
                            const unsigned short* __restrict__ rank,
                            unsigned int* __restrict__ epair, int E) {
  int e = blockIdx.x * blockDim.x + threadIdx.x;
  if (e < E) {
    int s = src[e], d = dst[e];
    float ds = (float)(unsigned int)degcnt[s] * (1.f / 33554432.f);
    float dd = (float)(unsigned int)degcnt[d] * (1.f / 33554432.f);
    float is = (ds > 0.f) ? rsqrtf(fmaxf(ds, 1e-12f)) : 0.f;
    float id_ = (dd > 0.f) ? rsqrtf(fmaxf(dd, 1e-12f)) : 0.f;
    float wh = -is * Ew[e] * id_;
    int pos = rowptr[d] + rank[e];
    epair[pos] = ((unsigned int)s << 16) | bf16rne(wh);
  }
}

// K5: gather  zt[n,p](bf16) = sum_{e: dst=n} w_hat(e) * fp8(x)[src, p]
//     one node per wave; lane l&31 owns bytes [12l,12l+12) of the 384B row;
//     halves split the edge list (indices == half mod 2); 4 edges per half in
//     flight per iteration (12 outstanding 12B loads); combined by shfl_xor(32).
__global__ __launch_bounds__(256) void gather_kernel(
    const int* __restrict__ rowptr, const unsigned int* __restrict__ epair,
    const unsigned char* __restrict__ xq, unsigned short* __restrict__ zt, int N) {
  int gt = blockIdx.x * blockDim.x + threadIdx.x;
  int n = gt >> 6;
  if (n >= N) return;
  int lane = gt & 63;
  int half = lane >> 5;
  int l = lane & 31;

  float acc[WW];
#pragma unroll
  for (int j = 0; j < WW; ++j) acc[j] = 0.f;

  int i = rowptr[n] + half;
  const int i1 = rowptr[n + 1];
  // 4 edges per half per iteration (8 per wave-iter)
  for (; i + 6 < i1; i += 8) {
    unsigned int e0 = epair[i];
    unsigned int e1 = epair[i + 2];
    unsigned int e2 = epair[i + 4];
    unsigned int e3 = epair[i + 6];
    const unsigned int* p0 = (const unsigned int*)(xq + (size_t)(e0 >> 16) * ROWB + l * 12);
    const unsigned int* p1 = (const unsigned int*)(xq + (size_t)(e1 >> 16) * ROWB + l * 12);
    const unsigned int* p2 = (const unsigned int*)(xq + (size_t)(e2 >> 16) * ROWB + l * 12);
    const unsigned int* p3 = (const unsigned int*)(xq + (size_t)(e3 >> 16) * ROWB + l * 12);
    unsigned int a0 = p0[0], a1 = p0[1], a2 = p0[2];
    unsigned int b0 = p1[0], b1 = p1[1], b2 = p1[2];
    unsigned int c0 = p2[0], c1 = p2[1], c2 = p2[2];
    unsigned int d0 = p3[0], d1 = p3[1], d2 = p3[2];
    float w0 = bf16tof(e0 & 0xffffu);
    float w1 = bf16tof(e1 & 0xffffu);
    float w2 = bf16tof(e2 & 0xffffu);
    float w3 = bf16tof(e3 & 0xffffu);
    dec4fma(a0, w0, acc + 0); dec4fma(a1, w0, acc + 4); dec4fma(a2, w0, acc + 8);
    dec4fma(b0, w1, acc + 0); dec4fma(b1, w1, acc + 4); dec4fma(b2, w1, acc + 8);
    dec4fma(c0, w2, acc + 0); dec4fma(c1, w2, acc + 4); dec4fma(c2, w2, acc + 8);
    dec4fma(d0, w3, acc + 0); dec4fma(d1, w3, acc + 4); dec4fma(d2, w3, acc + 8);
  }
  for (; i < i1; i += 2) {
    unsigned int e0 = epair[i];
    const unsigned int* p0 = (const unsigned int*)(xq + (size_t)(e0 >> 16) * ROWB + l * 12);
    unsigned int a0 = p0[0], a1 = p0[1], a2 = p0[2];
    float w0 = bf16tof(e0 & 0xffffu);
    dec4fma(a0, w0, acc + 0); dec4fma(a1, w0, acc + 4); dec4fma(a2, w0, acc + 8);
  }
#pragma unroll
  for (int j = 0; j < WW; ++j) acc[j] += __shfl_xor(acc[j], 32);

  if (half == 0) {
    unsigned short* q = zt + (size_t)n * ROWB + l * 12;
    short4v o0, o1, o2;
#pragma unroll
    for (int j = 0; j < 4; ++j) {
      o0[j] = (short)bf16rne(acc[j]);
      o1[j] = (short)bf16rne(acc[4 + j]);
      o2[j] = (short)bf16rne(acc[8 + j]);
    }
    *(short4v*)(q) = o0;
    *(short4v*)(q + 4) = o1;
    *(short4v*)(q + 8) = o2;
  }
}

// K6 (fused mix+conv, MFMA, rolling LDS ring): per wave, 16 nodes.
//  computeH(w): H[w] = bcheb[w] + X[w]@W0[w] + Z[w]@W1[w]  -> LDS ring slot w&3
//  convT(t):    OUT[t] = leaky( sum_k H[t+k-1] @ Wc[k] + bconv )
__global__ __launch_bounds__(256) void mc_kernel(
    const unsigned short* __restrict__ xt, const unsigned short* __restrict__ zt,
    const unsigned short* __restrict__ wb01, const unsigned short* __restrict__ wbc,
    const float* __restrict__ bcheb, const float* __restrict__ bconv,
    float* __restrict__ out, int N) {
  __shared__ __align__(16) unsigned short hts[4][4][16][40];  // [wave][ring][row][40-pad]
  const int wid = threadIdx.x >> 6;
  const int lane = threadIdx.x & 63;
  const int n0 = (blockIdx.x * 4 + wid) * 16;
  if (n0 >= N) return;
  const int kg = lane >> 4;
  const int arow = lane & 15;
  const int rrow = min(n0 + arow, N - 1);   // clamp tail reads

  short8v wcf0[3], wcf1[3];
#pragma unroll
  for (int k = 0; k < 3; ++k) {
    wcf0[k] = *(const short8v*)(wbc + (((k * 2 + 0) * 64 + lane) << 3));
    wcf1[k] = *(const short8v*)(wbc + (((k * 2 + 1) * 64 + lane) << 3));
  }
  const float bc0 = bconv[arow];
  const float bc1 = bconv[arow + 16];

  auto computeH = [&](int w) {
    const size_t fofs = (size_t)rrow * ROWB + w * CH + kg * 8;
    short8v xf = *(const short8v*)(xt + fofs);
    short8v zf = *(const short8v*)(zt + fofs);
    unsigned short* hrow = &hts[wid][w & 3][0][0];
#pragma unroll
    for (int h = 0; h < 2; ++h) {
      short8v w0f = *(const short8v*)(wb01 + ((((w * 2 + 0) * 2 + h) * 64 + lane) << 3));
      short8v w1f = *(const short8v*)(wb01 + ((((w * 2 + 1) * 2 + h) * 64 + lane) << 3));
      f32x4 acc = {0.f, 0.f, 0.f, 0.f};
      acc = __builtin_amdgcn_mfma_f32_16x16x32_bf16(xf, w0f, acc, 0, 0, 0);
      acc = __builtin_amdgcn_mfma_f32_16x16x32_bf16(zf, w1f, acc, 0, 0, 0);
      const int d = arow + (h << 4);
      const float bias = bcheb[w * CH + d];
#pragma unroll
      for (int r = 0; r < 4; ++r) {
        hrow[(kg * 4 + r) * 40 + d] = bf16rne(acc[r] + bias);
      }
    }
  };

  auto convT = [&](int t) {
    f32x4 a0 = {0.f, 0.f, 0.f, 0.f};
    f32x4 a1 = {0.f, 0.f, 0.f, 0.f};
#pragma unroll
    for (int k = 0; k < 3; ++k) {
      int w = t + k - 1;
      if (w < 0 || w >= WW) continue;
      short8v hf = *(const short8v*)(&hts[wid][w & 3][arow][kg * 8]);
      a0 = __builtin_amdgcn_mfma_f32_16x16x32_bf16(hf, wcf0[k], a0, 0, 0, 0);
      a1 = __builtin_amdgcn_mfma_f32_16x16x32_bf16(hf, wcf1[k], a1, 0, 0, 0);
    }
#pragma unroll
    for (int r = 0; r < 4; ++r) {
      int node = n0 + kg * 4 + r;
      if (node >= N) continue;               // guard tail writes
      float v0 = a0[r] + bc0;
      float v1 = a1[r] + bc1;
      v0 = (v0 >= 0.f) ? v0 : 0.01f * v0;
      v1 = (v1 >= 0.f) ? v1 : 0.01f * v1;
      size_t o = ((size_t)node * WW + t) * CH;
      out[o + arow] = v0;
      out[o + arow + 16] = v1;
    }
  };

  computeH(0);
  computeH(1);
  convT(0);
  for (int w = 2; w < WW; ++w) {
    computeH(w);
    convT(w - 1);
  }
  convT(WW - 1);
}

// ---------------------------------------------------------------------------
extern "C" void kernel_launch(void* const* d_in, const int* in_sizes, int n_in,
                              void* d_out, int out_size, void* d_ws, size_t ws_size,
                              hipStream_t stream) {
  const float* x     = (const float*)d_in[0];
  const int*   A     = (const int*)d_in[1];
  const float* Ew    = (const float*)d_in[2];
  const float* Wcheb = (const float*)d_in[3];
  const float* bcheb = (const float*)d_in[4];
  const float* Wconv = (const float*)d_in[5];
  const float* bconv = (const float*)d_in[6];
  float* out = (float*)d_out;

  const int E = in_sizes[2];
  const int N = in_sizes[0] / (WW * CH);
  const int* srcA = A;
  const int* dstA = A + E;

  char* ws = (char*)d_ws;
  size_t off = 0;
  auto alloc = [&](size_t bytes) -> void* {
    void* p = ws + off;
    off += (bytes + 255) / 256 * 256;
    return p;
  };
  unsigned long long* degcnt = (unsigned long long*)alloc((size_t)N * 8);
  int*   rowptr = (int*)alloc((size_t)(N + 1) * 4);
  int*   bsum   = (int*)alloc((size_t)SBT * 4);
  unsigned short* rank = (unsigned short*)alloc((size_t)E * 2);
  unsigned int* epair = (unsigned int*)alloc((size_t)E * 4);
  unsigned short* xt   = (unsigned short*)alloc((size_t)N * ROWB * 2);
  unsigned char*  xq   = (unsigned char*)alloc((size_t)N * ROWB);
  unsigned short* zt   = (unsigned short*)alloc((size_t)N * ROWB * 2);
  unsigned short* wb01 = (unsigned short*)alloc((size_t)24576 * 2);
  unsigned short* wbc  = (unsigned short*)alloc((size_t)3072 * 2);
  (void)ws_size;

  hipMemsetAsync(degcnt, 0, (size_t)N * 8, stream);

  const int nbR = (E + 255) / 256;
  const int nbx = (N * CH + 255) / 256;
  rankpack_kernel<<<nbR + 12 * nbx, 256, 0, stream>>>(
      dstA, Ew, degcnt, rank, x, Wcheb, Wconv, xt, xq, wb01, wbc, E, N, nbR, nbx);

  const int nb = (N + SBT - 1) / SBT;   // 196 <= 256 for N=50000
  scanA_kernel<<<nb, SBT, 0, stream>>>(degcnt, bsum, N);
  scanB_kernel<<<1, SBT, 0, stream>>>(bsum, rowptr, nb, N);
  scanC_kernel<<<nb, SBT, 0, stream>>>(degcnt, bsum, rowptr, N);

  fill_kernel<<<(E + 255) / 256, 256, 0, stream>>>(srcA, dstA, Ew, degcnt, rowptr, rank, epair, E);

  long long gtot = (long long)N * 64;
  gather_kernel<<<(unsigned)((gtot + 255) / 256), 256, 0, stream>>>(rowptr, epair, xq, zt, N);

  int ntiles = (N + 15) / 16;            // 16-node wave tiles
  int mcblocks = (ntiles + 3) / 4;       // 4 waves per block
  mc_kernel<<<mcblocks, 256, 0, stream>>>(xt, zt, wb01, wbc, bcheb, bconv, out, N);
}

// Round 12
// 255.357 us; speedup vs baseline: 1.4382x; 1.1807x over previous
//
#include <hip/hip_runtime.h>

#define WW 12
#define CH 32    // CIN == CMID == COUT == 32
#define KERN 3
#define SBT 256    // scan block size (two-level scan; needs ceil(N/SBT) <= SBT)
#define ROWB 384   // bytes per fp8 row = WW*CH; elements per bf16 row

typedef __attribute__((ext_vector_type(8))) short short8v;
typedef __attribute__((ext_vector_type(4))) short short4v;
typedef __attribute__((ext_vector_type(4))) float f32x4;

__device__ __forceinline__ unsigned short bf16rne(float v) {
  unsigned int u = __float_as_uint(v);
  return (unsigned short)((u + 0x7FFFu + ((u >> 16) & 1u)) >> 16);
}
__device__ __forceinline__ float bf16tof(unsigned int b) {
  return __uint_as_float(b << 16);
}

// exact-RNE f32 -> fp8 e4m3 (OCP, saturating, no NaN production)
__device__ __forceinline__ unsigned char fp8e4m3(float x) {
  unsigned int u = __float_as_uint(x);
  unsigned int s = (u >> 24) & 0x80u;
  float ax = fabsf(x);
  if (ax >= 464.f) return (unsigned char)(s | 0x7E);       // 448
  if (ax < 0.015625f) {                                    // subnormal: m = RNE(ax*512)
    int m = __float2int_rn(ax * 512.f);
    return (unsigned char)(s | (unsigned)m);               // m==8 carries to e=1,m=0
  }
  unsigned int au = u & 0x7fffffffu;
  au += 0x7FFFFu + ((au >> 20) & 1u);                      // RNE on 20 dropped bits
  int e = (int)(au >> 23) - 127 + 7;
  unsigned int m = (au >> 20) & 7u;
  if (e > 15 || (e == 15 && m == 7)) return (unsigned char)(s | 0x7E);
  return (unsigned char)(s | ((unsigned)e << 3) | m);
}

// decode 4 fp8 from one dword, fused multiply-accumulate into acc[0..3]
__device__ __forceinline__ void dec4fma(unsigned int u, float wh, float* acc) {
#if __has_builtin(__builtin_amdgcn_cvt_pk_f32_fp8)
  auto lo = __builtin_amdgcn_cvt_pk_f32_fp8((int)u, false);  // bytes 0,1
  auto hi = __builtin_amdgcn_cvt_pk_f32_fp8((int)u, true);   // bytes 2,3
  acc[0] = fmaf(wh, lo[0], acc[0]);
  acc[1] = fmaf(wh, lo[1], acc[1]);
  acc[2] = fmaf(wh, hi[0], acc[2]);
  acc[3] = fmaf(wh, hi[1], acc[3]);
#else
#pragma unroll
  for (int j = 0; j < 4; ++j) {
    unsigned int b = (u >> (8 * j)) & 0xffu;
    float f = __uint_as_float(((b & 0x80u) << 24) | ((b & 0x7fu) << 20)) * 0x1.0p120f;
    acc[j] = fmaf(wh, f, acc[j]);
  }
#endif
}

// ---------------------------------------------------------------------------
// K1 (FUSED rank + pack, INTERLEAVED 1:48 so both types co-resident):
//  rank blocks: 4 edges/thread -> 4 independent atomic chains in flight.
//    degcnt[dst] += (1<<32)|fix25(Ew); rank[e] = old>>32
//  pack blocks: x -> xt(bf16) + xq(fp8); w==0 also packs MFMA weight fragments.
__global__ void rankpack_kernel(const int* __restrict__ dst, const float* __restrict__ Ew,
                                unsigned long long* __restrict__ degcnt,
                                unsigned short* __restrict__ rank,
                                const float* __restrict__ x, const float* __restrict__ Wcheb,
                                const float* __restrict__ Wconv,
                                unsigned short* __restrict__ xt, unsigned char* __restrict__ xq,
                                unsigned short* __restrict__ wb01, unsigned short* __restrict__ wbc,
                                int E, int N, int npack, int nbx) {
  const int group = blockIdx.x / 49;
  const int slot = blockIdx.x % 49;
  if (slot == 48) {
    // ---- rank block: edges [group*1024, group*1024+1024) ----
    int base = group * 1024 + threadIdx.x;
    int e0 = base, e1 = base + 256, e2 = base + 512, e3 = base + 768;
#pragma unroll
    for (int u = 0; u < 4; ++u) {
      int e = base + u * 256;
      if (e < E) {
        unsigned int q = (unsigned int)__float2int_rn(Ew[e] * 33554432.f);
        unsigned long long old =
            atomicAdd(&degcnt[dst[e]], (1ULL << 32) | (unsigned long long)q);
        rank[e] = (unsigned short)(old >> 32);
      }
    }
    (void)e0; (void)e1; (void)e2; (void)e3;
    return;
  }
  // ---- pack block ----
  int pid = group * 48 + slot;
  if (pid >= npack) return;
  int w = pid / nbx;
  int id = (pid - w * nbx) * blockDim.x + threadIdx.x;
  if (id < N * CH) {
    int n = id >> 5;
    int c = id & 31;
    float v = x[(size_t)w * N * CH + id];
    xt[(size_t)n * ROWB + w * CH + c] = bf16rne(v);
    xq[(size_t)n * ROWB + w * CH + c] = fp8e4m3(v);
  }
  if (w == 0) {
    if (id < 12 * 2 * 2 * 64 * 8) {
      int j = id & 7, l = (id >> 3) & 63, h = (id >> 9) & 1, m = (id >> 10) & 1, ww = id >> 11;
      int k = ((l >> 4) << 3) + j;
      int d = (l & 15) + (h << 4);
      wb01[id] = bf16rne(Wcheb[((size_t)(ww * 2 + m) * 32 + k) * 32 + d]);
    } else if (id < 24576 + 3 * 2 * 64 * 8) {
      int i2 = id - 24576;
      int j = i2 & 7, l = (i2 >> 3) & 63, h = (i2 >> 9) & 1, k = i2 >> 10;
      int c = ((l >> 4) << 3) + j;
      int o = (l & 15) + (h << 4);
      wbc[i2] = bf16rne(Wconv[((size_t)(o * 32 + c)) * 3 + k]);
    }
  }
}

// K2a: per-block reduction of counts -> bsum[b]
__global__ void scanA_kernel(const unsigned long long* __restrict__ degcnt,
                             int* __restrict__ bsum, int N) {
  __shared__ int red[SBT];
  int i = blockIdx.x * SBT + threadIdx.x;
  red[threadIdx.x] = (i < N) ? (int)(degcnt[i] >> 32) : 0;
  __syncthreads();
  for (int o = SBT / 2; o > 0; o >>= 1) {
    if (threadIdx.x < o) red[threadIdx.x] += red[threadIdx.x + o];
    __syncthreads();
  }
  if (threadIdx.x == 0) bsum[blockIdx.x] = red[0];
}

// K2b: single-block exclusive scan of bsum (nb <= SBT); writes rowptr[N]=total
__global__ void scanB_kernel(int* __restrict__ bsum, int* __restrict__ rowptr,
                             int nb, int N) {
  __shared__ int tmp[SBT];
  int tid = threadIdx.x;
  int v = (tid < nb) ? bsum[tid] : 0;
  tmp[tid] = v;
  __syncthreads();
  for (int o = 1; o < SBT; o <<= 1) {
    int t = (tid >= o) ? tmp[tid - o] : 0;
    __syncthreads();
    tmp[tid] += t;
    __syncthreads();
  }
  if (tid < nb) bsum[tid] = tmp[tid] - v;        // exclusive block offsets
  if (tid == SBT - 1) rowptr[N] = tmp[SBT - 1];  // grand total
}

// K2c: per-block LDS ladder + block offset -> rowptr
__global__ void scanC_kernel(const unsigned long long* __restrict__ degcnt,
                             const int* __restrict__ bsum,
                             int* __restrict__ rowptr, int N) {
  __shared__ int tmp[SBT];
  int tid = threadIdx.x;
  int i = blockIdx.x * SBT + tid;
  int v = (i < N) ? (int)(degcnt[i] >> 32) : 0;
  tmp[tid] = v;
  __syncthreads();
  for (int o = 1; o < SBT; o <<= 1) {
    int t = (tid >= o) ? tmp[tid - o] : 0;
    __syncthreads();
    tmp[tid] += t;
    __syncthreads();
  }
  if (i < N) rowptr[i] = bsum[blockIdx.x] + tmp[tid] - v;
}

// K3: ATOMIC-FREE scatter: pos = rowptr[dst] + rank[e]; record = src<<16 | bf16(w_hat).
//     w_hat computed here from degcnt lo32 (L2-resident). Requires N <= 65536.
__global__ void fill_kernel(const int* __restrict__ src, const int* __restrict__ dst,
                            const float* __restrict__ Ew,
                            const unsigned long long* __restrict__ degcnt,
                            const int* __restrict__ rowptr,
                            const unsigned short* __restrict__ rank,
                            unsigned int* __restrict__ epair, int E) {
  int e = blockIdx.x * blockDim.x + threadIdx.x;
  if (e < E) {
    int s = src[e], d = dst[e];
    float ds = (float)(unsigned int)degcnt[s] * (1.f / 33554432.f);
    float dd = (float)(unsigned int)degcnt[d] * (1.f / 33554432.f);
    float is = (ds > 0.f) ? rsqrtf(fmaxf(ds, 1e-12f)) : 0.f;
    float id_ = (dd > 0.f) ? rsqrtf(fmaxf(dd, 1e-12f)) : 0.f;
    float wh = -is * Ew[e] * id_;
    int pos = rowptr[d] + rank[e];
    epair[pos] = ((unsigned int)s << 16) | bf16rne(wh);
  }
}

// K5: gather  zt[n,p](bf16) = sum_{e: dst=n} w_hat(e) * fp8(x)[src, p]
//     one node per wave; lane l&31 owns bytes [12l,12l+12) of the 384B row;
//     halves split the edge list (indices == half mod 2); 4 edges per half in
//     flight per iteration (12 outstanding 12B loads); combined by shfl_xor(32).
__global__ __launch_bounds__(256) void gather_kernel(
    const int* __restrict__ rowptr, const unsigned int* __restrict__ epair,
    const unsigned char* __restrict__ xq, unsigned short* __restrict__ zt, int N) {
  int gt = blockIdx.x * blockDim.x + threadIdx.x;
  int n = gt >> 6;
  if (n >= N) return;
  int lane = gt & 63;
  int half = lane >> 5;
  int l = lane & 31;

  float acc[WW];
#pragma unroll
  for (int j = 0; j < WW; ++j) acc[j] = 0.f;

  int i = rowptr[n] + half;
  const int i1 = rowptr[n + 1];
  // 4 edges per half per iteration (8 per wave-iter)
  for (; i + 6 < i1; i += 8) {
    unsigned int e0 = epair[i];
    unsigned int e1 = epair[i + 2];
    unsigned int e2 = epair[i + 4];
    unsigned int e3 = epair[i + 6];
    const unsigned int* p0 = (const unsigned int*)(xq + (size_t)(e0 >> 16) * ROWB + l * 12);
    const unsigned int* p1 = (const unsigned int*)(xq + (size_t)(e1 >> 16) * ROWB + l * 12);
    const unsigned int* p2 = (const unsigned int*)(xq + (size_t)(e2 >> 16) * ROWB + l * 12);
    const unsigned int* p3 = (const unsigned int*)(xq + (size_t)(e3 >> 16) * ROWB + l * 12);
    unsigned int a0 = p0[0], a1 = p0[1], a2 = p0[2];
    unsigned int b0 = p1[0], b1 = p1[1], b2 = p1[2];
    unsigned int c0 = p2[0], c1 = p2[1], c2 = p2[2];
    unsigned int d0 = p3[0], d1 = p3[1], d2 = p3[2];
    float w0 = bf16tof(e0 & 0xffffu);
    float w1 = bf16tof(e1 & 0xffffu);
    float w2 = bf16tof(e2 & 0xffffu);
    float w3 = bf16tof(e3 & 0xffffu);
    dec4fma(a0, w0, acc + 0); dec4fma(a1, w0, acc + 4); dec4fma(a2, w0, acc + 8);
    dec4fma(b0, w1, acc + 0); dec4fma(b1, w1, acc + 4); dec4fma(b2, w1, acc + 8);
    dec4fma(c0, w2, acc + 0); dec4fma(c1, w2, acc + 4); dec4fma(c2, w2, acc + 8);
    dec4fma(d0, w3, acc + 0); dec4fma(d1, w3, acc + 4); dec4fma(d2, w3, acc + 8);
  }
  for (; i < i1; i += 2) {
    unsigned int e0 = epair[i];
    const unsigned int* p0 = (const unsigned int*)(xq + (size_t)(e0 >> 16) * ROWB + l * 12);
    unsigned int a0 = p0[0], a1 = p0[1], a2 = p0[2];
    float w0 = bf16tof(e0 & 0xffffu);
    dec4fma(a0, w0, acc + 0); dec4fma(a1, w0, acc + 4); dec4fma(a2, w0, acc + 8);
  }
#pragma unroll
  for (int j = 0; j < WW; ++j) acc[j] += __shfl_xor(acc[j], 32);

  if (half == 0) {
    unsigned short* q = zt + (size_t)n * ROWB + l * 12;
    short4v o0, o1, o2;
#pragma unroll
    for (int j = 0; j < 4; ++j) {
      o0[j] = (short)bf16rne(acc[j]);
      o1[j] = (short)bf16rne(acc[4 + j]);
      o2[j] = (short)bf16rne(acc[8 + j]);
    }
    *(short4v*)(q) = o0;
    *(short4v*)(q + 4) = o1;
    *(short4v*)(q + 8) = o2;
  }
}

// K6 (fused mix+conv, MFMA, rolling LDS ring): per wave, 16 nodes.
//  computeH(w): H[w] = bcheb[w] + X[w]@W0[w] + Z[w]@W1[w]  -> LDS ring slot w&3
//  convT(t):    OUT[t] = leaky( sum_k H[t+k-1] @ Wc[k] + bconv )
__global__ __launch_bounds__(256) void mc_kernel(
    const unsigned short* __restrict__ xt, const unsigned short* __restrict__ zt,
    const unsigned short* __restrict__ wb01, const unsigned short* __restrict__ wbc,
    const float* __restrict__ bcheb, const float* __restrict__ bconv,
    float* __restrict__ out, int N) {
  __shared__ __align__(16) unsigned short hts[4][4][16][40];  // [wave][ring][row][40-pad]
  const int wid = threadIdx.x >> 6;
  const int lane = threadIdx.x & 63;
  const int n0 = (blockIdx.x * 4 + wid) * 16;
  if (n0 >= N) return;
  const int kg = lane >> 4;
  const int arow = lane & 15;
  const int rrow = min(n0 + arow, N - 1);   // clamp tail reads

  short8v wcf0[3], wcf1[3];
#pragma unroll
  for (int k = 0; k < 3; ++k) {
    wcf0[k] = *(const short8v*)(wbc + (((k * 2 + 0) * 64 + lane) << 3));
    wcf1[k] = *(const short8v*)(wbc + (((k * 2 + 1) * 64 + lane) << 3));
  }
  const float bc0 = bconv[arow];
  const float bc1 = bconv[arow + 16];

  auto computeH = [&](int w) {
    const size_t fofs = (size_t)rrow * ROWB + w * CH + kg * 8;
    short8v xf = *(const short8v*)(xt + fofs);
    short8v zf = *(const short8v*)(zt + fofs);
    unsigned short* hrow = &hts[wid][w & 3][0][0];
#pragma unroll
    for (int h = 0; h < 2; ++h) {
      short8v w0f = *(const short8v*)(wb01 + ((((w * 2 + 0) * 2 + h) * 64 + lane) << 3));
      short8v w1f = *(const short8v*)(wb01 + ((((w * 2 + 1) * 2 + h) * 64 + lane) << 3));
      f32x4 acc = {0.f, 0.f, 0.f, 0.f};
      acc = __builtin_amdgcn_mfma_f32_16x16x32_bf16(xf, w0f, acc, 0, 0, 0);
      acc = __builtin_amdgcn_mfma_f32_16x16x32_bf16(zf, w1f, acc, 0, 0, 0);
      const int d = arow + (h << 4);
      const float bias = bcheb[w * CH + d];
#pragma unroll
      for (int r = 0; r < 4; ++r) {
        hrow[(kg * 4 + r) * 40 + d] = bf16rne(acc[r] + bias);
      }
    }
  };

  auto convT = [&](int t) {
    f32x4 a0 = {0.f, 0.f, 0.f, 0.f};
    f32x4 a1 = {0.f, 0.f, 0.f, 0.f};
#pragma unroll
    for (int k = 0; k < 3; ++k) {
      int w = t + k - 1;
      if (w < 0 || w >= WW) continue;
      short8v hf = *(const short8v*)(&hts[wid][w & 3][arow][kg * 8]);
      a0 = __builtin_amdgcn_mfma_f32_16x16x32_bf16(hf, wcf0[k], a0, 0, 0, 0);
      a1 = __builtin_amdgcn_mfma_f32_16x16x32_bf16(hf, wcf1[k], a1, 0, 0, 0);
    }
#pragma unroll
    for (int r = 0; r < 4; ++r) {
      int node = n0 + kg * 4 + r;
      if (node >= N) continue;               // guard tail writes
      float v0 = a0[r] + bc0;
      float v1 = a1[r] + bc1;
      v0 = (v0 >= 0.f) ? v0 : 0.01f * v0;
      v1 = (v1 >= 0.f) ? v1 : 0.01f * v1;
      size_t o = ((size_t)node * WW + t) * CH;
      out[o + arow] = v0;
      out[o + arow + 16] = v1;
    }
  };

  computeH(0);
  computeH(1);
  convT(0);
  for (int w = 2; w < WW; ++w) {
    computeH(w);
    convT(w - 1);
  }
  convT(WW - 1);
}

// ---------------------------------------------------------------------------
extern "C" void kernel_launch(void* const* d_in, const int* in_sizes, int n_in,
                              void* d_out, int out_size, void* d_ws, size_t ws_size,
                              hipStream_t stream) {
  const float* x     = (const float*)d_in[0];
  const int*   A     = (const int*)d_in[1];
  const float* Ew    = (const float*)d_in[2];
  const float* Wcheb = (const float*)d_in[3];
  const float* bcheb = (const float*)d_in[4];
  const float* Wconv = (const float*)d_in[5];
  const float* bconv = (const float*)d_in[6];
  float* out = (float*)d_out;

  const int E = in_sizes[2];
  const int N = in_sizes[0] / (WW * CH);
  const int* srcA = A;
  const int* dstA = A + E;

  char* ws = (char*)d_ws;
  size_t off = 0;
  auto alloc = [&](size_t bytes) -> void* {
    void* p = ws + off;
    off += (bytes + 255) / 256 * 256;
    return p;
  };
  unsigned long long* degcnt = (unsigned long long*)alloc((size_t)N * 8);
  int*   rowptr = (int*)alloc((size_t)(N + 1) * 4);
  int*   bsum   = (int*)alloc((size_t)SBT * 4);
  unsigned short* rank = (unsigned short*)alloc((size_t)E * 2);
  unsigned int* epair = (unsigned int*)alloc((size_t)E * 4);
  unsigned short* xt   = (unsigned short*)alloc((size_t)N * ROWB * 2);
  unsigned char*  xq   = (unsigned char*)alloc((size_t)N * ROWB);
  unsigned short* zt   = (unsigned short*)alloc((size_t)N * ROWB * 2);
  unsigned short* wb01 = (unsigned short*)alloc((size_t)24576 * 2);
  unsigned short* wbc  = (unsigned short*)alloc((size_t)3072 * 2);
  (void)ws_size;

  hipMemsetAsync(degcnt, 0, (size_t)N * 8, stream);

  const int nbx = (N * CH + 255) / 256;       // pack blocks per w
  const int npack = 12 * nbx;
  const int nbR = (E + 1023) / 1024;          // rank blocks (4 edges/thread)
  const int ngroups = max(nbR, (npack + 47) / 48);
  rankpack_kernel<<<ngroups * 49, 256, 0, stream>>>(
      dstA, Ew, degcnt, rank, x, Wcheb, Wconv, xt, xq, wb01, wbc, E, N, npack, nbx);

  const int nb = (N + SBT - 1) / SBT;   // 196 <= 256 for N=50000
  scanA_kernel<<<nb, SBT, 0, stream>>>(degcnt, bsum, N);
  scanB_kernel<<<1, SBT, 0, stream>>>(bsum, rowptr, nb, N);
  scanC_kernel<<<nb, SBT, 0, stream>>>(degcnt, bsum, rowptr, N);

  fill_kernel<<<(E + 255) / 256, 256, 0, stream>>>(srcA, dstA, Ew, degcnt, rowptr, rank, epair, E);

  long long gtot = (long long)N * 64;
  gather_kernel<<<(unsigned)((gtot + 255) / 256), 256, 0, stream>>>(rowptr, epair, xq, zt, N);

  int ntiles = (N + 15) / 16;            // 16-node wave tiles
  int mcblocks = (ntiles + 3) / 4;       // 4 waves per block
  mc_kernel<<<mcblocks, 256, 0, stream>>>(xt, zt, wb01, wbc, bcheb, bconv, out, N);
}

// Round 13
// 249.729 us; speedup vs baseline: 1.4706x; 1.0225x over previous
//
#include <hip/hip_runtime.h>

#define WW 12
#define CH 32    // CIN == CMID == COUT == 32
#define KERN 3
#define SBT 256    // scan block size (two-level scan; needs ceil(N/SBT) <= SBT)
#define ROWB 384   // bytes per fp8 row = WW*CH; elements per bf16 row

typedef __attribute__((ext_vector_type(8))) short short8v;
typedef __attribute__((ext_vector_type(4))) short short4v;
typedef __attribute__((ext_vector_type(4))) float f32x4;

__device__ __forceinline__ unsigned short bf16rne(float v) {
  unsigned int u = __float_as_uint(v);
  return (unsigned short)((u + 0x7FFFu + ((u >> 16) & 1u)) >> 16);
}
__device__ __forceinline__ float bf16tof(unsigned int b) {
  return __uint_as_float(b << 16);
}

// exact-RNE f32 -> fp8 e4m3 (OCP, saturating, no NaN production)
__device__ __forceinline__ unsigned char fp8e4m3(float x) {
  unsigned int u = __float_as_uint(x);
  unsigned int s = (u >> 24) & 0x80u;
  float ax = fabsf(x);
  if (ax >= 464.f) return (unsigned char)(s | 0x7E);       // 448
  if (ax < 0.015625f) {                                    // subnormal: m = RNE(ax*512)
    int m = __float2int_rn(ax * 512.f);
    return (unsigned char)(s | (unsigned)m);               // m==8 carries to e=1,m=0
  }
  unsigned int au = u & 0x7fffffffu;
  au += 0x7FFFFu + ((au >> 20) & 1u);                      // RNE on 20 dropped bits
  int e = (int)(au >> 23) - 127 + 7;
  unsigned int m = (au >> 20) & 7u;
  if (e > 15 || (e == 15 && m == 7)) return (unsigned char)(s | 0x7E);
  return (unsigned char)(s | ((unsigned)e << 3) | m);
}

// decode 4 fp8 from one dword, fused multiply-accumulate into acc[0..3]
__device__ __forceinline__ void dec4fma(unsigned int u, float wh, float* acc) {
#if __has_builtin(__builtin_amdgcn_cvt_pk_f32_fp8)
  auto lo = __builtin_amdgcn_cvt_pk_f32_fp8((int)u, false);  // bytes 0,1
  auto hi = __builtin_amdgcn_cvt_pk_f32_fp8((int)u, true);   // bytes 2,3
  acc[0] = fmaf(wh, lo[0], acc[0]);
  acc[1] = fmaf(wh, lo[1], acc[1]);
  acc[2] = fmaf(wh, hi[0], acc[2]);
  acc[3] = fmaf(wh, hi[1], acc[3]);
#else
#pragma unroll
  for (int j = 0; j < 4; ++j) {
    unsigned int b = (u >> (8 * j)) & 0xffu;
    float f = __uint_as_float(((b & 0x80u) << 24) | ((b & 0x7fu) << 20)) * 0x1.0p120f;
    acc[j] = fmaf(wh, f, acc[j]);
  }
#endif
}

// ---------------------------------------------------------------------------
// K1 (FUSED rank + pack, INTERLEAVED 6 pack : 1 rank, both co-resident):
//  rank blocks: 4 edges/thread -> 4 independent atomic chains in flight.
//    degcnt[dst] += (1<<32)|fix25(Ew); rank[e] = old>>32
//  pack blocks: 8 elems/thread (2x float4 in, 16B bf16 + 8B fp8 out).
//  pid >= npx: weight-fragment packing (108 blocks).
__global__ void rankpack_kernel(const int* __restrict__ dst, const float* __restrict__ Ew,
                                unsigned long long* __restrict__ degcnt,
                                unsigned short* __restrict__ rank,
                                const float* __restrict__ x, const float* __restrict__ Wcheb,
                                const float* __restrict__ Wconv,
                                unsigned short* __restrict__ xt, unsigned char* __restrict__ xq,
                                unsigned short* __restrict__ wb01, unsigned short* __restrict__ wbc,
                                int E, int N, int npackTot, int npx) {
  const int group = blockIdx.x / 7;
  const int slot = blockIdx.x % 7;
  if (slot == 6) {
    // ---- rank block: edges [group*1024, group*1024+1024) ----
    int base = group * 1024 + threadIdx.x;
#pragma unroll
    for (int u = 0; u < 4; ++u) {
      int e = base + u * 256;
      if (e < E) {
        unsigned int q = (unsigned int)__float2int_rn(Ew[e] * 33554432.f);
        unsigned long long old =
            atomicAdd(&degcnt[dst[e]], (1ULL << 32) | (unsigned long long)q);
        rank[e] = (unsigned short)(old >> 32);
      }
    }
    return;
  }
  int pid = group * 6 + slot;
  if (pid >= npackTot) return;
  if (pid < npx) {
    // ---- pack block: 8 consecutive flat elements per thread ----
    long long f = ((long long)pid * 256 + threadIdx.x) * 8;   // flat idx into x (w,n,c)
    const long long T = (long long)WW * N * CH;
    if (f >= T) return;
    float4 v0 = *(const float4*)(x + f);
    float4 v1 = *(const float4*)(x + f + 4);
    int w = (int)(f / ((long long)N * CH));
    int rem = (int)(f - (long long)w * N * CH);
    int n = rem >> 5;
    int c = rem & 31;                                   // multiple of 8
    size_t o = (size_t)n * ROWB + w * CH + c;
    short4v h0, h1;
    h0[0] = (short)bf16rne(v0.x); h0[1] = (short)bf16rne(v0.y);
    h0[2] = (short)bf16rne(v0.z); h0[3] = (short)bf16rne(v0.w);
    h1[0] = (short)bf16rne(v1.x); h1[1] = (short)bf16rne(v1.y);
    h1[2] = (short)bf16rne(v1.z); h1[3] = (short)bf16rne(v1.w);
    *(short4v*)(xt + o) = h0;
    *(short4v*)(xt + o + 4) = h1;
    unsigned int q0 = (unsigned int)fp8e4m3(v0.x) | ((unsigned int)fp8e4m3(v0.y) << 8) |
                      ((unsigned int)fp8e4m3(v0.z) << 16) | ((unsigned int)fp8e4m3(v0.w) << 24);
    unsigned int q1 = (unsigned int)fp8e4m3(v1.x) | ((unsigned int)fp8e4m3(v1.y) << 8) |
                      ((unsigned int)fp8e4m3(v1.z) << 16) | ((unsigned int)fp8e4m3(v1.w) << 24);
    *(unsigned int*)(xq + o) = q0;
    *(unsigned int*)(xq + o + 4) = q1;
    return;
  }
  // ---- weight-fragment block ----
  int id = (pid - npx) * 256 + threadIdx.x;
  if (id < 12 * 2 * 2 * 64 * 8) {
    int j = id & 7, l = (id >> 3) & 63, h = (id >> 9) & 1, m = (id >> 10) & 1, ww = id >> 11;
    int k = ((l >> 4) << 3) + j;
    int d = (l & 15) + (h << 4);
    wb01[id] = bf16rne(Wcheb[((size_t)(ww * 2 + m) * 32 + k) * 32 + d]);
  } else if (id < 24576 + 3 * 2 * 64 * 8) {
    int i2 = id - 24576;
    int j = i2 & 7, l = (i2 >> 3) & 63, h = (i2 >> 9) & 1, k = i2 >> 10;
    int c = ((l >> 4) << 3) + j;
    int o = (l & 15) + (h << 4);
    wbc[i2] = bf16rne(Wconv[((size_t)(o * 32 + c)) * 3 + k]);
  }
}

// K2a: per-block reduction of counts -> bsum[b]
__global__ void scanA_kernel(const unsigned long long* __restrict__ degcnt,
                             int* __restrict__ bsum, int N) {
  __shared__ int red[SBT];
  int i = blockIdx.x * SBT + threadIdx.x;
  red[threadIdx.x] = (i < N) ? (int)(degcnt[i] >> 32) : 0;
  __syncthreads();
  for (int o = SBT / 2; o > 0; o >>= 1) {
    if (threadIdx.x < o) red[threadIdx.x] += red[threadIdx.x + o];
    __syncthreads();
  }
  if (threadIdx.x == 0) bsum[blockIdx.x] = red[0];
}

// K2b: single-block exclusive scan of bsum (nb <= SBT); writes rowptr[N]=total
__global__ void scanB_kernel(int* __restrict__ bsum, int* __restrict__ rowptr,
                             int nb, int N) {
  __shared__ int tmp[SBT];
  int tid = threadIdx.x;
  int v = (tid < nb) ? bsum[tid] : 0;
  tmp[tid] = v;
  __syncthreads();
  for (int o = 1; o < SBT; o <<= 1) {
    int t = (tid >= o) ? tmp[tid - o] : 0;
    __syncthreads();
    tmp[tid] += t;
    __syncthreads();
  }
  if (tid < nb) bsum[tid] = tmp[tid] - v;        // exclusive block offsets
  if (tid == SBT - 1) rowptr[N] = tmp[SBT - 1];  // grand total
}

// K2c: per-block LDS ladder + block offset -> rowptr
__global__ void scanC_kernel(const unsigned long long* __restrict__ degcnt,
                             const int* __restrict__ bsum,
                             int* __restrict__ rowptr, int N) {
  __shared__ int tmp[SBT];
  int tid = threadIdx.x;
  int i = blockIdx.x * SBT + tid;
  int v = (i < N) ? (int)(degcnt[i] >> 32) : 0;
  tmp[tid] = v;
  __syncthreads();
  for (int o = 1; o < SBT; o <<= 1) {
    int t = (tid >= o) ? tmp[tid - o] : 0;
    __syncthreads();
    tmp[tid] += t;
    __syncthreads();
  }
  if (i < N) rowptr[i] = bsum[blockIdx.x] + tmp[tid] - v;
}

// K3: ATOMIC-FREE scatter: pos = rowptr[dst] + rank[e]; record = src<<16 | bf16(w_hat).
//     w_hat computed here from degcnt lo32 (L2-resident). Requires N <= 65536.
__global__ void fill_kernel(const int* __restrict__ src, const int* __restrict__ dst,
                            const float* __restrict__ Ew,
                            const unsigned long long* __restrict__ degcnt,
                            const int* __restrict__ rowptr,
                            const unsigned short* __restrict__ rank,
                            unsigned int* __restrict__ epair, int E) {
  int e = blockIdx.x * blockDim.x + threadIdx.x;
  if (e < E) {
    int s = src[e], d = dst[e];
    float ds = (float)(unsigned int)degcnt[s] * (1.f / 33554432.f);
    float dd = (float)(unsigned int)degcnt[d] * (1.f / 33554432.f);
    float is = (ds > 0.f) ? rsqrtf(fmaxf(ds, 1e-12f)) : 0.f;
    float id_ = (dd > 0.f) ? rsqrtf(fmaxf(dd, 1e-12f)) : 0.f;
    float wh = -is * Ew[e] * id_;
    int pos = rowptr[d] + rank[e];
    epair[pos] = ((unsigned int)s << 16) | bf16rne(wh);
  }
}

// K5: gather  zt[n,p](bf16) = sum_{e: dst=n} w_hat(e) * fp8(x)[src, p]
//     one node per wave; lane l&31 owns bytes [12l,12l+12) of the 384B row;
//     halves split the edge list (indices == half mod 2); 4 edges per half in
//     flight per iteration (12 outstanding 12B loads); combined by shfl_xor(32).
__global__ __launch_bounds__(256) void gather_kernel(
    const int* __restrict__ rowptr, const unsigned int* __restrict__ epair,
    const unsigned char* __restrict__ xq, unsigned short* __restrict__ zt, int N) {
  int gt = blockIdx.x * blockDim.x + threadIdx.x;
  int n = gt >> 6;
  if (n >= N) return;
  int lane = gt & 63;
  int half = lane >> 5;
  int l = lane & 31;

  float acc[WW];
#pragma unroll
  for (int j = 0; j < WW; ++j) acc[j] = 0.f;

  int i = rowptr[n] + half;
  const int i1 = rowptr[n + 1];
  // 4 edges per half per iteration (8 per wave-iter)
  for (; i + 6 < i1; i += 8) {
    unsigned int e0 = epair[i];
    unsigned int e1 = epair[i + 2];
    unsigned int e2 = epair[i + 4];
    unsigned int e3 = epair[i + 6];
    const unsigned int* p0 = (const unsigned int*)(xq + (size_t)(e0 >> 16) * ROWB + l * 12);
    const unsigned int* p1 = (const unsigned int*)(xq + (size_t)(e1 >> 16) * ROWB + l * 12);
    const unsigned int* p2 = (const unsigned int*)(xq + (size_t)(e2 >> 16) * ROWB + l * 12);
    const unsigned int* p3 = (const unsigned int*)(xq + (size_t)(e3 >> 16) * ROWB + l * 12);
    unsigned int a0 = p0[0], a1 = p0[1], a2 = p0[2];
    unsigned int b0 = p1[0], b1 = p1[1], b2 = p1[2];
    unsigned int c0 = p2[0], c1 = p2[1], c2 = p2[2];
    unsigned int d0 = p3[0], d1 = p3[1], d2 = p3[2];
    float w0 = bf16tof(e0 & 0xffffu);
    float w1 = bf16tof(e1 & 0xffffu);
    float w2 = bf16tof(e2 & 0xffffu);
    float w3 = bf16tof(e3 & 0xffffu);
    dec4fma(a0, w0, acc + 0); dec4fma(a1, w0, acc + 4); dec4fma(a2, w0, acc + 8);
    dec4fma(b0, w1, acc + 0); dec4fma(b1, w1, acc + 4); dec4fma(b2, w1, acc + 8);
    dec4fma(c0, w2, acc + 0); dec4fma(c1, w2, acc + 4); dec4fma(c2, w2, acc + 8);
    dec4fma(d0, w3, acc + 0); dec4fma(d1, w3, acc + 4); dec4fma(d2, w3, acc + 8);
  }
  for (; i < i1; i += 2) {
    unsigned int e0 = epair[i];
    const unsigned int* p0 = (const unsigned int*)(xq + (size_t)(e0 >> 16) * ROWB + l * 12);
    unsigned int a0 = p0[0], a1 = p0[1], a2 = p0[2];
    float w0 = bf16tof(e0 & 0xffffu);
    dec4fma(a0, w0, acc + 0); dec4fma(a1, w0, acc + 4); dec4fma(a2, w0, acc + 8);
  }
#pragma unroll
  for (int j = 0; j < WW; ++j) acc[j] += __shfl_xor(acc[j], 32);

  if (half == 0) {
    unsigned short* q = zt + (size_t)n * ROWB + l * 12;
    short4v o0, o1, o2;
#pragma unroll
    for (int j = 0; j < 4; ++j) {
      o0[j] = (short)bf16rne(acc[j]);
      o1[j] = (short)bf16rne(acc[4 + j]);
      o2[j] = (short)bf16rne(acc[8 + j]);
    }
    *(short4v*)(q) = o0;
    *(short4v*)(q + 4) = o1;
    *(short4v*)(q + 8) = o2;
  }
}

// K6 (fused mix+conv, MFMA, rolling LDS ring): per wave, 16 nodes.
//  computeH(w): H[w] = bcheb[w] + X[w]@W0[w] + Z[w]@W1[w]  -> LDS ring slot w&3
//  convT(t):    OUT[t] = leaky( sum_k H[t+k-1] @ Wc[k] + bconv )
__global__ __launch_bounds__(256) void mc_kernel(
    const unsigned short* __restrict__ xt, const unsigned short* __restrict__ zt,
    const unsigned short* __restrict__ wb01, const unsigned short* __restrict__ wbc,
    const float* __restrict__ bcheb, const float* __restrict__ bconv,
    float* __restrict__ out, int N) {
  __shared__ __align__(16) unsigned short hts[4][4][16][40];  // [wave][ring][row][40-pad]
  const int wid = threadIdx.x >> 6;
  const int lane = threadIdx.x & 63;
  const int n0 = (blockIdx.x * 4 + wid) * 16;
  if (n0 >= N) return;
  const int kg = lane >> 4;
  const int arow = lane & 15;
  const int rrow = min(n0 + arow, N - 1);   // clamp tail reads

  short8v wcf0[3], wcf1[3];
#pragma unroll
  for (int k = 0; k < 3; ++k) {
    wcf0[k] = *(const short8v*)(wbc + (((k * 2 + 0) * 64 + lane) << 3));
    wcf1[k] = *(const short8v*)(wbc + (((k * 2 + 1) * 64 + lane) << 3));
  }
  const float bc0 = bconv[arow];
  const float bc1 = bconv[arow + 16];

  auto computeH = [&](int w) {
    const size_t fofs = (size_t)rrow * ROWB + w * CH + kg * 8;
    short8v xf = *(const short8v*)(xt + fofs);
    short8v zf = *(const short8v*)(zt + fofs);
    unsigned short* hrow = &hts[wid][w & 3][0][0];
#pragma unroll
    for (int h = 0; h < 2; ++h) {
      short8v w0f = *(const short8v*)(wb01 + ((((w * 2 + 0) * 2 + h) * 64 + lane) << 3));
      short8v w1f = *(const short8v*)(wb01 + ((((w * 2 + 1) * 2 + h) * 64 + lane) << 3));
      f32x4 acc = {0.f, 0.f, 0.f, 0.f};
      acc = __builtin_amdgcn_mfma_f32_16x16x32_bf16(xf, w0f, acc, 0, 0, 0);
      acc = __builtin_amdgcn_mfma_f32_16x16x32_bf16(zf, w1f, acc, 0, 0, 0);
      const int d = arow + (h << 4);
      const float bias = bcheb[w * CH + d];
#pragma unroll
      for (int r = 0; r < 4; ++r) {
        hrow[(kg * 4 + r) * 40 + d] = bf16rne(acc[r] + bias);
      }
    }
  };

  auto convT = [&](int t) {
    f32x4 a0 = {0.f, 0.f, 0.f, 0.f};
    f32x4 a1 = {0.f, 0.f, 0.f, 0.f};
#pragma unroll
    for (int k = 0; k < 3; ++k) {
      int w = t + k - 1;
      if (w < 0 || w >= WW) continue;
      short8v hf = *(const short8v*)(&hts[wid][w & 3][arow][kg * 8]);
      a0 = __builtin_amdgcn_mfma_f32_16x16x32_bf16(hf, wcf0[k], a0, 0, 0, 0);
      a1 = __builtin_amdgcn_mfma_f32_16x16x32_bf16(hf, wcf1[k], a1, 0, 0, 0);
    }
#pragma unroll
    for (int r = 0; r < 4; ++r) {
      int node = n0 + kg * 4 + r;
      if (node >= N) continue;               // guard tail writes
      float v0 = a0[r] + bc0;
      float v1 = a1[r] + bc1;
      v0 = (v0 >= 0.f) ? v0 : 0.01f * v0;
      v1 = (v1 >= 0.f) ? v1 : 0.01f * v1;
      size_t o = ((size_t)node * WW + t) * CH;
      out[o + arow] = v0;
      out[o + arow + 16] = v1;
    }
  };

  computeH(0);
  computeH(1);
  convT(0);
  for (int w = 2; w < WW; ++w) {
    computeH(w);
    convT(w - 1);
  }
  convT(WW - 1);
}

// ---------------------------------------------------------------------------
extern "C" void kernel_launch(void* const* d_in, const int* in_sizes, int n_in,
                              void* d_out, int out_size, void* d_ws, size_t ws_size,
                              hipStream_t stream) {
  const float* x     = (const float*)d_in[0];
  const int*   A     = (const int*)d_in[1];
  const float* Ew    = (const float*)d_in[2];
  const float* Wcheb = (const float*)d_in[3];
  const float* bcheb = (const float*)d_in[4];
  const float* Wconv = (const float*)d_in[5];
  const float* bconv = (const float*)d_in[6];
  float* out = (float*)d_out;

  const int E = in_sizes[2];
  const int N = in_sizes[0] / (WW * CH);
  const int* srcA = A;
  const int* dstA = A + E;

  char* ws = (char*)d_ws;
  size_t off = 0;
  auto alloc = [&](size_t bytes) -> void* {
    void* p = ws + off;
    off += (bytes + 255) / 256 * 256;
    return p;
  };
  unsigned long long* degcnt = (unsigned long long*)alloc((size_t)N * 8);
  int*   rowptr = (int*)alloc((size_t)(N + 1) * 4);
  int*   bsum   = (int*)alloc((size_t)SBT * 4);
  unsigned short* rank = (unsigned short*)alloc((size_t)E * 2);
  unsigned int* epair = (unsigned int*)alloc((size_t)E * 4);
  unsigned short* xt   = (unsigned short*)alloc((size_t)N * ROWB * 2);
  unsigned char*  xq   = (unsigned char*)alloc((size_t)N * ROWB);
  unsigned short* zt   = (unsigned short*)alloc((size_t)N * ROWB * 2);
  unsigned short* wb01 = (unsigned short*)alloc((size_t)24576 * 2);
  unsigned short* wbc  = (unsigned short*)alloc((size_t)3072 * 2);
  (void)ws_size;

  hipMemsetAsync(degcnt, 0, (size_t)N * 8, stream);

  const long long T = (long long)WW * N * CH;             // 19.2M
  const int npx = (int)((T + 2047) / 2048);               // pack blocks (8 elem/thread)
  const int nwb = (24576 + 3072 + 255) / 256;             // weight blocks
  const int npackTot = npx + nwb;
  const int nbR = (E + 1023) / 1024;                      // rank blocks (4 edges/thread)
  const int ngroups = max(nbR, (npackTot + 5) / 6);
  rankpack_kernel<<<ngroups * 7, 256, 0, stream>>>(
      dstA, Ew, degcnt, rank, x, Wcheb, Wconv, xt, xq, wb01, wbc, E, N, npackTot, npx);

  const int nb = (N + SBT - 1) / SBT;   // 196 <= 256 for N=50000
  scanA_kernel<<<nb, SBT, 0, stream>>>(degcnt, bsum, N);
  scanB_kernel<<<1, SBT, 0, stream>>>(bsum, rowptr, nb, N);
  scanC_kernel<<<nb, SBT, 0, stream>>>(degcnt, bsum, rowptr, N);

  fill_kernel<<<(E + 255) / 256, 256, 0, stream>>>(srcA, dstA, Ew, degcnt, rowptr, rank, epair, E);

  long long gtot = (long long)N * 64;
  gather_kernel<<<(unsigned)((gtot + 255) / 256), 256, 0, stream>>>(rowptr, epair, xq, zt, N);

  int ntiles = (N + 15) / 16;            // 16-node wave tiles
  int mcblocks = (ntiles + 3) / 4;       // 4 waves per block
  mc_kernel<<<mcblocks, 256, 0, stream>>>(xt, zt, wb01, wbc, bcheb, bconv, out, N);
}